// Round 3
// baseline (3298.087 us; speedup 1.0000x reference)
//
#include <hip/hip_runtime.h>
#include <math.h>

// ---------------------------------------------------------------------------
// AttentionFlow v3.
//  pass1 (edges1): fp32 score kernel with LDS-staged weights (shared across
//    the block's 4 waves; round-1 was L2-BW-bound on 4x-redundant W streams).
//    fp32 kept: top-k selection needs exact logits.
//  pass0 (edges0): split-f16 MFMA pipeline (hi/lo _Float16, 3 MFMAs/product,
//    ~1e-6 logit error): GEMM1 (gather+split -> Lr packed), GEMM2 (Lr@Wc ->
//    Rout f32), GEMM3 (gather+split, epilogue fuses dot with Rout -> logits0).
//    f16 (not bf16) because mfma_*_f16 takes _Float16 vectors on every LLVM;
//    the bf16 builtin's V8y operand type was the round-2 compile failure.
// ---------------------------------------------------------------------------

#define NNODES 100000
#define DDIM   256
#define NH     512
#define NGROUP 64
#define EPG    1024
#define E1N    65536
#define E0N    65536
#define KTOP   256
#define TE     32

typedef __attribute__((ext_vector_type(8))) _Float16 h8v;
typedef __attribute__((ext_vector_type(4))) float f32x4;
typedef __attribute__((ext_vector_type(4))) int i4v;

__device__ __forceinline__ float lrelu(float x) { return x > 0.0f ? x : 0.01f * x; }

__device__ __forceinline__ unsigned fenc(float f) {
  unsigned u = __float_as_uint(f);
  return (u & 0x80000000u) ? ~u : (u | 0x80000000u);
}
__device__ __forceinline__ float fdec(unsigned k) {
  unsigned u = (k & 0x80000000u) ? (k & 0x7FFFFFFFu) : ~k;
  return __uint_as_float(u);
}

// split one f32 into hi/lo f16 bit patterns
__device__ __forceinline__ void splitf(float v, unsigned short& h, unsigned short& l) {
  _Float16 hh = (_Float16)v;
  _Float16 ll = (_Float16)(v - (float)hh);
  h = __builtin_bit_cast(unsigned short, hh);
  l = __builtin_bit_cast(unsigned short, ll);
}

// split one f32 -> (hi16<<16)|lo16
__device__ __forceinline__ unsigned packsplit(float v) {
  unsigned short h, l;
  splitf(v, h, l);
  return ((unsigned)h << 16) | (unsigned)l;
}

__device__ __forceinline__ f32x4 mfma16(h8v a, h8v b, f32x4 c) {
  return __builtin_amdgcn_mfma_f32_16x16x32_f16(a, b, c, 0, 0, 0);
}

#define FMA8(ACC, EI, X, W0, W1)                                    \
  ACC[(EI)*8+0] += (X) * (W0).x; ACC[(EI)*8+1] += (X) * (W0).y;     \
  ACC[(EI)*8+2] += (X) * (W0).z; ACC[(EI)*8+3] += (X) * (W0).w;     \
  ACC[(EI)*8+4] += (X) * (W1).x; ACC[(EI)*8+5] += (X) * (W1).y;     \
  ACC[(EI)*8+6] += (X) * (W1).z; ACC[(EI)*8+7] += (X) * (W1).w;

// ---------------------------------------------------------------------------
// qterm[g][o] = b[o] + qs[g] @ W[512:768] + qr[g] @ W[768:1024]
// ---------------------------------------------------------------------------
__global__ __launch_bounds__(512)
void qterm_kernel(const float* __restrict__ qse, const float* __restrict__ qre,
                  const float* __restrict__ Wl, const float* __restrict__ bl,
                  const float* __restrict__ Wr, const float* __restrict__ br,
                  float* __restrict__ qtl, float* __restrict__ qtr)
{
  const int g = blockIdx.x;
  const int o = threadIdx.x;
  __shared__ float sq[DDIM];
  __shared__ float sr[DDIM];
  if (o < DDIM) sq[o] = qse[(size_t)g * DDIM + o];
  else          sr[o - DDIM] = qre[(size_t)g * DDIM + (o - DDIM)];
  __syncthreads();
  float al = bl[o], ar = br[o];
  for (int k = 0; k < DDIM; ++k) {
    float a = sq[k], b = sr[k];
    al += a * Wl[(size_t)(512 + k) * NH + o] + b * Wl[(size_t)(768 + k) * NH + o];
    ar += a * Wr[(size_t)(512 + k) * NH + o] + b * Wr[(size_t)(768 + k) * NH + o];
  }
  qtl[(size_t)g * NH + o] = al;
  qtr[(size_t)g * NH + o] = ar;
}

// ---------------------------------------------------------------------------
// fp32 score kernel (edges1 / pass1).
// 32 edges/block, 256 threads, 4 waves x 8 edges.
// Lane o-mapping: outs {4*lane..4*lane+3} and {256+4*lane..+3}.
// Weights staged via LDS in 16-row chunks, shared by all waves.
// ---------------------------------------------------------------------------
__global__ __launch_bounds__(256, 2)
void score_kernel(const int* __restrict__ edges,
                  const float* __restrict__ emb,
                  const float* __restrict__ rel,
                  const float* __restrict__ Wl,
                  const float* __restrict__ Wr,
                  const float* __restrict__ Wc,
                  const float* __restrict__ bc,
                  const float* __restrict__ qtl,
                  const float* __restrict__ qtr,
                  float* __restrict__ logits)
{
  __shared__ float wbuf[16 * 512];   // 32 KB weight chunk
  __shared__ float xs[64][36];       // k-major gathered X chunk
  __shared__ float rs[16][36];       // k-major leaky(r) chunk (C phase)
  __shared__ int   meta[32][3];

  const int tid  = threadIdx.x;
  const int lane = tid & 63;
  const int wid  = tid >> 6;
  const int eb   = wid * 8;          // this wave's edge base
  const int e0   = blockIdx.x * TE;
  const int le   = tid >> 3, ls = tid & 7;

  if (tid < TE) {
    const int* er = edges + (size_t)(e0 + tid) * 8;
    meta[tid][0] = er[6]; meta[tid][1] = er[7]; meta[tid][2] = er[0];
  }

  auto stage_w = [&](const float* Wsrc, int k0) {
    const int r = tid >> 4, c0 = (tid & 15) * 32;
    const float* src = Wsrc + (size_t)(k0 + r) * NH + c0;
    float* dst = wbuf + r * 512 + c0;
#pragma unroll
    for (int q = 0; q < 8; ++q) {
      int cc = ((q + (tid & 15)) & 7) * 4;       // staggered to spread banks
      *(float4*)(dst + cc) = *(const float4*)(src + cc);
    }
  };

  auto stage_x = [&](const float* emb_, int metacol, int c64) {
    int kb = c64 * 64;
    const float* src;
    if (kb < 256) src = emb_ + (size_t)meta[le][metacol] * DDIM + kb;
    else          src = rel + (size_t)(e0 + le) * DDIM + (kb - 256);
    float4 a = *(const float4*)(src + ls * 8);
    float4 b = *(const float4*)(src + ls * 8 + 4);
    float v[8] = {a.x, a.y, a.z, a.w, b.x, b.y, b.z, b.w};
#pragma unroll
    for (int q = 0; q < 8; ++q) xs[ls * 8 + q][le] = v[q];
  };

  auto fma16f = [&](float* acc, const float (*xp)[36], int xoff) {
#pragma unroll 2
    for (int kk = 0; kk < 16; ++kk) {
      const float* wr0 = wbuf + kk * 512 + lane * 4;
      float4 w0 = *(const float4*)wr0;
      float4 w1 = *(const float4*)(wr0 + 256);
      float4 x0 = *(const float4*)(&xp[xoff + kk][eb]);
      float4 x1 = *(const float4*)(&xp[xoff + kk][eb + 4]);
      float xv[8] = {x0.x, x0.y, x0.z, x0.w, x1.x, x1.y, x1.z, x1.w};
#pragma unroll
      for (int ei = 0; ei < 8; ++ei) {
        FMA8(acc, ei, xv[ei], w0, w1)
      }
    }
  };

  // ---------------- R phase ----------------
  float accR[64];
#pragma unroll
  for (int q = 0; q < 64; ++q) accR[q] = 0.0f;
  for (int c = 0; c < 32; ++c) {
    __syncthreads();
    stage_w(Wr, c * 16);
    if ((c & 3) == 0) stage_x(emb, 1, c >> 2);
    __syncthreads();
    fma16f(accR, xs, (c & 3) * 16);
  }
#pragma unroll
  for (int ei = 0; ei < 8; ++ei) {
    const float* q = qtr + (size_t)meta[eb + ei][2] * NH;
    float4 q0 = *(const float4*)(q + lane * 4);
    float4 q1 = *(const float4*)(q + 256 + lane * 4);
    accR[ei*8+0] = lrelu(accR[ei*8+0] + q0.x);
    accR[ei*8+1] = lrelu(accR[ei*8+1] + q0.y);
    accR[ei*8+2] = lrelu(accR[ei*8+2] + q0.z);
    accR[ei*8+3] = lrelu(accR[ei*8+3] + q0.w);
    accR[ei*8+4] = lrelu(accR[ei*8+4] + q1.x);
    accR[ei*8+5] = lrelu(accR[ei*8+5] + q1.y);
    accR[ei*8+6] = lrelu(accR[ei*8+6] + q1.z);
    accR[ei*8+7] = lrelu(accR[ei*8+7] + q1.w);
  }

  // ---------------- C phase: r_out = leaky_r @ Wc + bc ----------------
  float accC[64];
  {
    float4 b0 = *(const float4*)(bc + lane * 4);
    float4 b1 = *(const float4*)(bc + 256 + lane * 4);
#pragma unroll
    for (int ei = 0; ei < 8; ++ei) {
      accC[ei*8+0] = b0.x; accC[ei*8+1] = b0.y; accC[ei*8+2] = b0.z; accC[ei*8+3] = b0.w;
      accC[ei*8+4] = b1.x; accC[ei*8+5] = b1.y; accC[ei*8+6] = b1.z; accC[ei*8+7] = b1.w;
    }
  }
  for (int c = 0; c < 32; ++c) {
    __syncthreads();
    stage_w(Wc, c * 16);
    {
      const int half = c >> 4;       // 0: outs<256, 1: outs>=256
      const int cc = c & 15;
      if ((lane >> 2) == cc) {
        const int d = lane & 3;
#pragma unroll
        for (int ei = 0; ei < 8; ++ei)
#pragma unroll
          for (int q = 0; q < 4; ++q)
            rs[d * 4 + q][eb + ei] = accR[ei * 8 + half * 4 + q];
      }
    }
    __syncthreads();
    fma16f(accC, rs, 0);
  }

  // ---------------- L phase ----------------
  float accL[64];
#pragma unroll
  for (int q = 0; q < 64; ++q) accL[q] = 0.0f;
  for (int c = 0; c < 32; ++c) {
    __syncthreads();
    stage_w(Wl, c * 16);
    if ((c & 3) == 0) stage_x(emb, 0, c >> 2);
    __syncthreads();
    fma16f(accL, xs, (c & 3) * 16);
  }
#pragma unroll
  for (int ei = 0; ei < 8; ++ei) {
    const float* q = qtl + (size_t)meta[eb + ei][2] * NH;
    float4 q0 = *(const float4*)(q + lane * 4);
    float4 q1 = *(const float4*)(q + 256 + lane * 4);
    accL[ei*8+0] = lrelu(accL[ei*8+0] + q0.x);
    accL[ei*8+1] = lrelu(accL[ei*8+1] + q0.y);
    accL[ei*8+2] = lrelu(accL[ei*8+2] + q0.z);
    accL[ei*8+3] = lrelu(accL[ei*8+3] + q0.w);
    accL[ei*8+4] = lrelu(accL[ei*8+4] + q1.x);
    accL[ei*8+5] = lrelu(accL[ei*8+5] + q1.y);
    accL[ei*8+6] = lrelu(accL[ei*8+6] + q1.z);
    accL[ei*8+7] = lrelu(accL[ei*8+7] + q1.w);
  }

  // ---------------- dot + wave reduce ----------------
  float p[8];
#pragma unroll
  for (int ei = 0; ei < 8; ++ei) {
    float s = 0.0f;
#pragma unroll
    for (int oi = 0; oi < 8; ++oi) s += accL[ei * 8 + oi] * accC[ei * 8 + oi];
    p[ei] = s;
  }
#pragma unroll
  for (int off = 1; off < 64; off <<= 1) {
#pragma unroll
    for (int ei = 0; ei < 8; ++ei) p[ei] += __shfl_xor(p[ei], off);
  }
#pragma unroll
  for (int ei = 0; ei < 8; ++ei)
    if (lane == ei) logits[e0 + eb + ei] = p[ei];
}

// ---------------------------------------------------------------------------
// weight prep: Wt{H,L}[o][k] = splitf16(W[k][o]) for Wl[0:512], Wr[0:512], Wc
// ---------------------------------------------------------------------------
__global__ __launch_bounds__(256)
void wprep_kernel(const float* __restrict__ Wl, const float* __restrict__ Wr,
                  const float* __restrict__ Wc,
                  unsigned short* __restrict__ WltH, unsigned short* __restrict__ WltL,
                  unsigned short* __restrict__ WrtH, unsigned short* __restrict__ WrtL,
                  unsigned short* __restrict__ WctH, unsigned short* __restrict__ WctL)
{
  __shared__ float shv[32][33];
  const int mtx = blockIdx.y;
  const int ti = blockIdx.x >> 4;     // k tile
  const int tj = blockIdx.x & 15;     // o tile
  const float* W = mtx == 0 ? Wl : (mtx == 1 ? Wr : Wc);
  unsigned short* OH = mtx == 0 ? WltH : (mtx == 1 ? WrtH : WctH);
  unsigned short* OL = mtx == 0 ? WltL : (mtx == 1 ? WrtL : WctL);
  const int t = threadIdx.x;
  const int r = t >> 3, c4 = (t & 7) * 4;
  *(float4*)&shv[r][c4] = *(const float4*)(W + (size_t)(ti * 32 + r) * 512 + tj * 32 + c4);
  __syncthreads();
  unsigned short h[4], l[4];
#pragma unroll
  for (int q = 0; q < 4; ++q) splitf(shv[c4 + q][r], h[q], l[q]);
  const size_t off = (size_t)(tj * 32 + r) * 512 + ti * 32 + c4;
  *(uint2*)(OH + off) = make_uint2((unsigned)h[0] | ((unsigned)h[1] << 16),
                                   (unsigned)h[2] | ((unsigned)h[3] << 16));
  *(uint2*)(OL + off) = make_uint2((unsigned)l[0] | ((unsigned)l[1] << 16),
                                   (unsigned)l[2] | ((unsigned)l[3] << 16));
}

// ---------------------------------------------------------------------------
// split-f16 MFMA GEMM, 128x128 tile, 4 waves (2x2), 4x4 16x16x32 tiles/wave.
// MODE 0: A = gather([emb1[j]|rel0]) split on the fly; epi: leaky(+qtr) -> packed Lr
// MODE 1: A = unpack(LrPack);                          epi: +bc -> Rout f32
// MODE 2: A = gather([emb1[i]|rel0]);                  epi: leaky(+qtl), dot with
//         Rout, 16-lane reduce, atomicAdd -> logits0
// ---------------------------------------------------------------------------
template<int MODE>
__global__ __launch_bounds__(256)
void gemm_kernel(const int* __restrict__ edges, int ebase,
                 const float* __restrict__ emb, const float* __restrict__ rel,
                 const unsigned* __restrict__ Apack,
                 const unsigned short* __restrict__ BtH,
                 const unsigned short* __restrict__ BtL,
                 const float* __restrict__ qt, const float* __restrict__ bcv,
                 unsigned* __restrict__ OutU,
                 const float* __restrict__ Rin,
                 float* __restrict__ logits)
{
  __shared__ int sidx[128];
  __shared__ int sgrp[128];
  __shared__ unsigned bounce[64][132];

  const int tid  = threadIdx.x;
  const int lane = tid & 63;
  const int wid  = tid >> 6;
  const int wm = wid >> 1, wn = wid & 1;
  const int mb = blockIdx.x >> 2, nb = blockIdx.x & 3;
  const int rb = mb * 128;                 // chunk-local row base
  const int arow = lane & 15;
  const int kgrp = (lane >> 4) * 8;
  const int col0 = nb * 128 + wn * 64;
  const int row0 = wm * 64;

  if (MODE != 1) {
    if (tid < 128) {
      const int* er = edges + (size_t)(ebase + rb + tid) * 8;
      sidx[tid] = er[MODE == 0 ? 7 : 6];
      sgrp[tid] = er[0];
    }
    __syncthreads();
  }

  f32x4 acc[4][4];
#pragma unroll
  for (int a = 0; a < 4; ++a)
#pragma unroll
    for (int b = 0; b < 4; ++b) acc[a][b] = (f32x4)0.0f;

  for (int ks = 0; ks < 16; ++ks) {
    const int k0 = ks * 32 + kgrp;
    h8v ah[4], al[4], bh[4], bl[4];
#pragma unroll
    for (int nt = 0; nt < 4; ++nt) {
      const size_t boff = (size_t)(col0 + nt * 16 + arow) * 512 + k0;
      bh[nt] = *(const h8v*)(BtH + boff);
      bl[nt] = *(const h8v*)(BtL + boff);
    }
#pragma unroll
    for (int mt = 0; mt < 4; ++mt) {
      const int rl = row0 + mt * 16 + arow;
      h8v h, l;
      if (MODE == 1) {
        const unsigned* ap = Apack + (size_t)(rb + rl) * 512 + k0;
        uint4 p0 = *(const uint4*)ap;
        uint4 p1 = *(const uint4*)(ap + 4);
        unsigned u[8] = {p0.x, p0.y, p0.z, p0.w, p1.x, p1.y, p1.z, p1.w};
        i4v hv, lv;
#pragma unroll
        for (int d = 0; d < 4; ++d) {
          hv[d] = (int)((u[2*d] >> 16) | (u[2*d+1] & 0xffff0000u));
          lv[d] = (int)((u[2*d] & 0xffffu) | (u[2*d+1] << 16));
        }
        h = __builtin_bit_cast(h8v, hv);
        l = __builtin_bit_cast(h8v, lv);
      } else {
        const float* src = (k0 < 256)
            ? emb + (size_t)sidx[rl] * DDIM + k0
            : rel + (size_t)(ebase + rb + rl) * DDIM + (k0 - 256);
        float4 f0 = *(const float4*)src;
        float4 f1 = *(const float4*)(src + 4);
        float v[8] = {f0.x, f0.y, f0.z, f0.w, f1.x, f1.y, f1.z, f1.w};
#pragma unroll
        for (int d = 0; d < 8; ++d) {
          _Float16 hh = (_Float16)v[d];
          h[d] = hh;
          l[d] = (_Float16)(v[d] - (float)hh);
        }
      }
      ah[mt] = h; al[mt] = l;
    }
#pragma unroll
    for (int mt = 0; mt < 4; ++mt)
#pragma unroll
      for (int nt = 0; nt < 4; ++nt) {
        acc[mt][nt] = mfma16(ah[mt], bh[nt], acc[mt][nt]);
        acc[mt][nt] = mfma16(ah[mt], bl[nt], acc[mt][nt]);
        acc[mt][nt] = mfma16(al[mt], bh[nt], acc[mt][nt]);
      }
  }

  if (MODE == 2) {
#pragma unroll
    for (int mt = 0; mt < 4; ++mt) {
#pragma unroll
      for (int reg = 0; reg < 4; ++reg) {
        const int rl = row0 + mt * 16 + (lane >> 4) * 4 + reg;
        const int g = sgrp[rl];
        float s = 0.0f;
#pragma unroll
        for (int nt = 0; nt < 4; ++nt) {
          const int c = col0 + nt * 16 + arow;
          float v = lrelu(acc[mt][nt][reg] + qt[(size_t)g * NH + c]);
          s += v * Rin[(size_t)(rb + rl) * 512 + c];
        }
        s += __shfl_xor(s, 1); s += __shfl_xor(s, 2);
        s += __shfl_xor(s, 4); s += __shfl_xor(s, 8);
        if ((lane & 15) == 0)
          atomicAdd(logits + ebase + rb + rl, s);
      }
    }
    return;
  }

  unsigned pk[4][4][4];
#pragma unroll
  for (int mt = 0; mt < 4; ++mt)
#pragma unroll
    for (int nt = 0; nt < 4; ++nt) {
      const int c = col0 + nt * 16 + arow;
#pragma unroll
      for (int reg = 0; reg < 4; ++reg) {
        const int rl = row0 + mt * 16 + (lane >> 4) * 4 + reg;
        float v = acc[mt][nt][reg];
        if (MODE == 0) {
          v = lrelu(v + qt[(size_t)sgrp[rl] * NH + c]);
          pk[mt][nt][reg] = packsplit(v);
        } else {
          pk[mt][nt][reg] = __float_as_uint(v + bcv[c]);
        }
      }
    }
#pragma unroll
  for (int half = 0; half < 2; ++half) {
    __syncthreads();
    if (wm == half) {
#pragma unroll
      for (int mt = 0; mt < 4; ++mt)
#pragma unroll
        for (int nt = 0; nt < 4; ++nt) {
          const int cl = wn * 64 + nt * 16 + arow;
#pragma unroll
          for (int reg = 0; reg < 4; ++reg)
            bounce[mt * 16 + (lane >> 4) * 4 + reg][cl] = pk[mt][nt][reg];
        }
    }
    __syncthreads();
    {
      const int r = tid >> 2, cb = (tid & 3) * 32;
      unsigned* dst = OutU + (size_t)(rb + half * 64 + r) * 512 + nb * 128 + cb;
      const unsigned* s0 = &bounce[r][cb];
#pragma unroll
      for (int q = 0; q < 8; ++q)
        *(uint4*)(dst + q * 4) = *(const uint4*)(s0 + q * 4);
    }
  }
}

// ---------------------------------------------------------------------------
// segment softmax helpers
// ---------------------------------------------------------------------------
__global__ void smax_max_kernel(const int* __restrict__ edges, const float* __restrict__ logits,
                                unsigned* __restrict__ mkey, int E)
{
  int e = blockIdx.x * blockDim.x + threadIdx.x;
  if (e < E) atomicMax(mkey + edges[(size_t)e * 8 + 6], fenc(logits[e]));
}

__global__ void smax_exp_kernel(const int* __restrict__ edges, const float* __restrict__ logits,
                                const unsigned* __restrict__ mkey, float* __restrict__ ssum,
                                float* __restrict__ sm, int E)
{
  int e = blockIdx.x * blockDim.x + threadIdx.x;
  if (e < E) {
    int s = edges[(size_t)e * 8 + 6];
    float ev = expf(logits[e] - fdec(mkey[s]));
    sm[e] = ev;
    atomicAdd(ssum + s, ev);
  }
}

__global__ void smax_norm_kernel(const int* __restrict__ edges, const float* __restrict__ ssum,
                                 float* __restrict__ sm, const float* __restrict__ nscore,
                                 float* __restrict__ ta, int E)
{
  int e = blockIdx.x * blockDim.x + threadIdx.x;
  if (e < E) {
    int s = edges[(size_t)e * 8 + 6];
    float v = sm[e] / ssum[s];
    sm[e] = v;
    if (ta) ta[e] = v * nscore[s];
  }
}

// ---------------------------------------------------------------------------
// per-group top-256 of 1024 (desc value, ties -> low idx), bitonic sort
// ---------------------------------------------------------------------------
__global__ __launch_bounds__(256)
void topk_kernel(const float* __restrict__ ta, const float* __restrict__ sm1,
                 const int* __restrict__ edges1,
                 float* __restrict__ out0, float* __restrict__ out2,
                 float* __restrict__ out3, float* __restrict__ smp,
                 int* __restrict__ prn_i, int* __restrict__ prn_j,
                 int* __restrict__ cnt1)
{
  __shared__ float v[EPG];
  __shared__ int   ix[EPG];
  const int g = blockIdx.x, tid = threadIdx.x;
  for (int t = tid; t < EPG; t += 256) { v[t] = ta[(size_t)g * EPG + t]; ix[t] = t; }
  __syncthreads();
  for (int k = 2; k <= EPG; k <<= 1) {
    for (int j = k >> 1; j > 0; j >>= 1) {
      for (int t = tid; t < EPG; t += 256) {
        int l = t ^ j;
        if (l > t) {
          float va = v[t], vb = v[l];
          int ia = ix[t], ib = ix[l];
          bool aFirst = (va > vb) || (va == vb && ia < ib);
          bool up = ((t & k) == 0);
          bool sw = up ? !aFirst : aFirst;
          if (sw) { v[t] = vb; ix[t] = ib; v[l] = va; ix[l] = ia; }
        }
      }
      __syncthreads();
    }
  }
  const int r = tid;
  const int oi = ix[r];
  const float val = v[r];
  const int orig = g * EPG + oi;
  out3[(size_t)g * KTOP + r] = (float)orig;
  const int* er = edges1 + (size_t)orig * 8;
#pragma unroll
  for (int c = 0; c < 8; ++c)
    out2[((size_t)(g * KTOP + r)) * 8 + c] = (float)er[c];
  const int ii = er[6], jj = er[7];
  const float smv = sm1[orig];
  smp[(size_t)g * KTOP + r] = smv;
  prn_i[(size_t)g * KTOP + r] = ii;
  prn_j[(size_t)g * KTOP + r] = jj;
  atomicAdd(out0 + jj, smv * val);
  atomicAdd(cnt1 + jj, 1);
}

__global__ void scatter_kernel(const int* __restrict__ idx_i, int si,
                               const int* __restrict__ idx_j, int sj,
                               const float* __restrict__ w,
                               const float* __restrict__ semb,
                               float* __restrict__ agg)
{
  const int e = blockIdx.x;
  const int o = threadIdx.x;
  const int i = idx_i[(size_t)e * si];
  const int j = idx_j[(size_t)e * sj];
  atomicAdd(agg + (size_t)j * DDIM + o, w[e] * semb[(size_t)i * DDIM + o]);
}

__global__ void cnt_kernel(const int* __restrict__ idx_j, int sj, int* __restrict__ cnt, int E)
{
  int e = blockIdx.x * blockDim.x + threadIdx.x;
  if (e < E) atomicAdd(cnt + idx_j[(size_t)e * sj], 1);
}

__global__ void combine_kernel(const float* __restrict__ mememb, const int* __restrict__ cnt,
                               float* __restrict__ agg)
{
  size_t id = (size_t)blockIdx.x * 256 + threadIdx.x;
  if (cnt[id >> 8] == 0) agg[id] = mememb[id];
}

// ---------------------------------------------------------------------------
// final: out[r] = leaky( (cnt0[r]>0 ? agg0[r] : emb1[r]) @ Wlin + blin )
// ---------------------------------------------------------------------------
__global__ __launch_bounds__(256, 2)
void final_kernel(const float* __restrict__ emb1, const float* __restrict__ agg0,
                  const int* __restrict__ cnt0, const float* __restrict__ Wlin,
                  const float* __restrict__ blin, float* __restrict__ out)
{
  __shared__ float As[64][68];
  __shared__ int scnt[64];
  const int tid = threadIdx.x;
  const int r0 = blockIdx.x * 64;
  const int ob = (tid & 31) * 8;
  const int rb = (tid >> 5) * 8;
  if (tid < 64) {
    int r = r0 + tid;
    scnt[tid] = (r < NNODES) ? cnt0[r] : 0;
  }
  float acc[64];
  {
    float4 b0 = *(const float4*)(blin + ob);
    float4 b1 = *(const float4*)(blin + ob + 4);
    float bb2[8] = {b0.x, b0.y, b0.z, b0.w, b1.x, b1.y, b1.z, b1.w};
#pragma unroll
    for (int ri = 0; ri < 8; ++ri)
#pragma unroll
      for (int oi = 0; oi < 8; ++oi) acc[ri * 8 + oi] = bb2[oi];
  }
  const int le = tid >> 2, ls = tid & 3;
  for (int c = 0; c < 4; ++c) {
    __syncthreads();
    {
      int r = r0 + le;
      int rc = (r < NNODES) ? r : 0;
      const float* base = (scnt[le] > 0) ? agg0 : emb1;
      const float4* s4 = (const float4*)(base + (size_t)rc * DDIM + c * 64 + ls * 16);
      float4 a0 = s4[0], a1 = s4[1], a2 = s4[2], a3 = s4[3];
      *(float4*)&As[le][ls * 16]      = a0;
      *(float4*)&As[le][ls * 16 + 4]  = a1;
      *(float4*)&As[le][ls * 16 + 8]  = a2;
      *(float4*)&As[le][ls * 16 + 12] = a3;
    }
    __syncthreads();
    const float* wb = Wlin + (size_t)(c * 64) * DDIM + ob;
#pragma unroll 2
    for (int k = 0; k < 64; ++k) {
      float4 w0 = *(const float4*)(wb + (size_t)k * DDIM);
      float4 w1 = *(const float4*)(wb + (size_t)k * DDIM + 4);
#pragma unroll
      for (int ri = 0; ri < 8; ++ri) {
        float x = As[rb + ri][k];
        FMA8(acc, ri, x, w0, w1)
      }
    }
  }
#pragma unroll
  for (int ri = 0; ri < 8; ++ri) {
    int r = r0 + rb + ri;
    if (r < NNODES) {
      float4 o0 = make_float4(lrelu(acc[ri*8+0]), lrelu(acc[ri*8+1]),
                              lrelu(acc[ri*8+2]), lrelu(acc[ri*8+3]));
      float4 o1 = make_float4(lrelu(acc[ri*8+4]), lrelu(acc[ri*8+5]),
                              lrelu(acc[ri*8+6]), lrelu(acc[ri*8+7]));
      *(float4*)(out + (size_t)r * DDIM + ob)     = o0;
      *(float4*)(out + (size_t)r * DDIM + ob + 4) = o1;
    }
  }
}

// ---------------------------------------------------------------------------
extern "C" void kernel_launch(void* const* d_in, const int* in_sizes, int n_in,
                              void* d_out, int out_size, void* d_ws, size_t ws_size,
                              hipStream_t stream)
{
  (void)in_sizes; (void)n_in; (void)out_size;

  const float* node_score = (const float*)d_in[1];
  const int*   edges0 = (const int*)d_in[2];
  const int*   edges1 = (const int*)d_in[3];
  const float* rel0   = (const float*)d_in[4];
  const float* rel1   = (const float*)d_in[5];
  const float* mememb = (const float*)d_in[6];
  const float* qse    = (const float*)d_in[7];
  const float* qre    = (const float*)d_in[8];
  const float* Wl     = (const float*)d_in[9];
  const float* bl     = (const float*)d_in[10];
  const float* Wr     = (const float*)d_in[11];
  const float* br     = (const float*)d_in[12];
  const float* Wc     = (const float*)d_in[13];
  const float* bc     = (const float*)d_in[14];
  const float* Wlin   = (const float*)d_in[15];
  const float* blin   = (const float*)d_in[16];

  float* out0 = (float*)d_out;
  float* out1 = out0 + NNODES;
  float* out2 = out1 + (size_t)NNODES * DDIM;
  float* out3 = out2 + (size_t)NGROUP * KTOP * 8;

  char* wptr = (char*)d_ws;
  auto alloc = [&](size_t bytes) -> char* {
    char* p = wptr;
    wptr += (bytes + 255) & ~(size_t)255;
    return p;
  };
  float*    qtl     = (float*)alloc((size_t)NGROUP * NH * 4);
  float*    qtr     = (float*)alloc((size_t)NGROUP * NH * 4);
  float*    logits1 = (float*)alloc((size_t)E1N * 4);
  float*    sm1     = (float*)alloc((size_t)E1N * 4);
  float*    ta      = (float*)alloc((size_t)E1N * 4);
  float*    logits0 = (float*)alloc((size_t)E0N * 4);
  float*    sm0     = (float*)alloc((size_t)E0N * 4);
  unsigned* mkey    = (unsigned*)alloc((size_t)NNODES * 4);
  float*    ssum    = (float*)alloc((size_t)NNODES * 4);
  int*      cnt1    = (int*)alloc((size_t)NNODES * 4);
  int*      cnt0    = (int*)alloc((size_t)NNODES * 4);
  float*    smp     = (float*)alloc((size_t)NGROUP * KTOP * 4);
  int*      prn_i   = (int*)alloc((size_t)NGROUP * KTOP * 4);
  int*      prn_j   = (int*)alloc((size_t)NGROUP * KTOP * 4);
  float*    agg1    = (float*)alloc((size_t)NNODES * DDIM * 4);   // emb1

  unsigned short* WltH = (unsigned short*)alloc((size_t)512 * 512 * 2);
  unsigned short* WltL = (unsigned short*)alloc((size_t)512 * 512 * 2);
  unsigned short* WrtH = (unsigned short*)alloc((size_t)512 * 512 * 2);
  unsigned short* WrtL = (unsigned short*)alloc((size_t)512 * 512 * 2);
  unsigned short* WctH = (unsigned short*)alloc((size_t)512 * 512 * 2);
  unsigned short* WctL = (unsigned short*)alloc((size_t)512 * 512 * 2);

  // adaptive chunking of the pass-0 GEMM pipeline to fit workspace
  size_t used = (size_t)(wptr - (char*)d_ws);
  int nchunks = 4;
  while (nchunks < 32 && used + 2 * ((size_t)(E0N / nchunks) * 512 * 4 + 256) > ws_size)
    nchunks <<= 1;
  const int CE = E0N / nchunks;
  unsigned* LrPack = (unsigned*)alloc((size_t)CE * 512 * 4);
  float*    Rout   = (float*)alloc((size_t)CE * 512 * 4);

  // ---- pass 1 ----
  (void)hipMemsetAsync(agg1, 0, (size_t)NNODES * DDIM * 4, stream);
  (void)hipMemsetAsync(cnt1, 0, (size_t)NNODES * 4, stream);
  (void)hipMemsetAsync(mkey, 0, (size_t)NNODES * 4, stream);
  (void)hipMemsetAsync(ssum, 0, (size_t)NNODES * 4, stream);
  (void)hipMemsetAsync(out0, 0, (size_t)NNODES * 4, stream);

  qterm_kernel<<<NGROUP, 512, 0, stream>>>(qse, qre, Wl, bl, Wr, br, qtl, qtr);
  {
    dim3 g(256, 3);
    wprep_kernel<<<g, 256, 0, stream>>>(Wl, Wr, Wc, WltH, WltL, WrtH, WrtL, WctH, WctL);
  }
  score_kernel<<<E1N / TE, 256, 0, stream>>>(edges1, mememb, rel1, Wl, Wr, Wc, bc,
                                             qtl, qtr, logits1);
  smax_max_kernel<<<E1N / 256, 256, 0, stream>>>(edges1, logits1, mkey, E1N);
  smax_exp_kernel<<<E1N / 256, 256, 0, stream>>>(edges1, logits1, mkey, ssum, sm1, E1N);
  smax_norm_kernel<<<E1N / 256, 256, 0, stream>>>(edges1, ssum, sm1, node_score, ta, E1N);
  topk_kernel<<<NGROUP, 256, 0, stream>>>(ta, sm1, edges1, out0, out2, out3,
                                          smp, prn_i, prn_j, cnt1);
  scatter_kernel<<<NGROUP * KTOP, 256, 0, stream>>>(prn_i, 1, prn_j, 1, smp, mememb, agg1);
  combine_kernel<<<NNODES, 256, 0, stream>>>(mememb, cnt1, agg1);   // agg1 = emb1

  // ---- pass 0 ----
  (void)hipMemsetAsync(mkey, 0, (size_t)NNODES * 4, stream);
  (void)hipMemsetAsync(ssum, 0, (size_t)NNODES * 4, stream);
  (void)hipMemsetAsync(cnt0, 0, (size_t)NNODES * 4, stream);
  (void)hipMemsetAsync(out1, 0, (size_t)NNODES * DDIM * 4, stream);
  (void)hipMemsetAsync(logits0, 0, (size_t)E0N * 4, stream);

  for (int ch = 0; ch < nchunks; ++ch) {
    const int eb = ch * CE;
    dim3 g((CE / 128) * 4);
    gemm_kernel<0><<<g, 256, 0, stream>>>(edges0, eb, agg1, rel0, nullptr,
                                          WrtH, WrtL, qtr, nullptr,
                                          LrPack, nullptr, nullptr);
    gemm_kernel<1><<<g, 256, 0, stream>>>(edges0, eb, agg1, rel0, LrPack,
                                          WctH, WctL, nullptr, bc,
                                          (unsigned*)Rout, nullptr, nullptr);
    gemm_kernel<2><<<g, 256, 0, stream>>>(edges0, eb, agg1, rel0, nullptr,
                                          WltH, WltL, qtl, nullptr,
                                          nullptr, Rout, logits0);
  }

  smax_max_kernel<<<E0N / 256, 256, 0, stream>>>(edges0, logits0, mkey, E0N);
  smax_exp_kernel<<<E0N / 256, 256, 0, stream>>>(edges0, logits0, mkey, ssum, sm0, E0N);
  smax_norm_kernel<<<E0N / 256, 256, 0, stream>>>(edges0, ssum, sm0, nullptr, nullptr, E0N);
  scatter_kernel<<<E0N, 256, 0, stream>>>(edges0 + 6, 8, edges0 + 7, 8, sm0, agg1, out1);
  cnt_kernel<<<E0N / 256, 256, 0, stream>>>(edges0 + 7, 8, cnt0, E0N);
  final_kernel<<<(NNODES + 63) / 64, 256, 0, stream>>>(agg1, out1, cnt0, Wlin, blin, out1);
}

// Round 4
// 2825.975 us; speedup vs baseline: 1.1671x; 1.1671x over previous
//
#include <hip/hip_runtime.h>
#include <math.h>

// ---------------------------------------------------------------------------
// AttentionFlow v4.
//  pass1 (edges1): fp32 score kernel with LDS-staged weights (shared across
//    the block's 4 waves). fp32 kept: top-k selection needs exact logits.
//    v4 fix: C-phase staging used accR[.. + half*4 ..] with RUNTIME half ->
//    compiler demoted accR to scratch (3.5 GB WRITE_SIZE in v3 counters).
//    Now HALF is a macro literal; all register-array indices compile-time.
//  pass0 (edges0): split-f16 MFMA pipeline (hi/lo _Float16, 3 MFMAs/product):
//    GEMM1 (gather+split -> Lr packed), GEMM2 (Lr@Wc -> Rout f32),
//    GEMM3 (gather+split, epilogue fuses dot with Rout -> logits0).
// ---------------------------------------------------------------------------

#define NNODES 100000
#define DDIM   256
#define NH     512
#define NGROUP 64
#define EPG    1024
#define E1N    65536
#define E0N    65536
#define KTOP   256
#define TE     32

typedef __attribute__((ext_vector_type(8))) _Float16 h8v;
typedef __attribute__((ext_vector_type(4))) float f32x4;
typedef __attribute__((ext_vector_type(4))) int i4v;

__device__ __forceinline__ float lrelu(float x) { return x > 0.0f ? x : 0.01f * x; }

__device__ __forceinline__ unsigned fenc(float f) {
  unsigned u = __float_as_uint(f);
  return (u & 0x80000000u) ? ~u : (u | 0x80000000u);
}
__device__ __forceinline__ float fdec(unsigned k) {
  unsigned u = (k & 0x80000000u) ? (k & 0x7FFFFFFFu) : ~k;
  return __uint_as_float(u);
}

// split one f32 into hi/lo f16 bit patterns
__device__ __forceinline__ void splitf(float v, unsigned short& h, unsigned short& l) {
  _Float16 hh = (_Float16)v;
  _Float16 ll = (_Float16)(v - (float)hh);
  h = __builtin_bit_cast(unsigned short, hh);
  l = __builtin_bit_cast(unsigned short, ll);
}

// split one f32 -> (hi16<<16)|lo16
__device__ __forceinline__ unsigned packsplit(float v) {
  unsigned short h, l;
  splitf(v, h, l);
  return ((unsigned)h << 16) | (unsigned)l;
}

__device__ __forceinline__ f32x4 mfma16(h8v a, h8v b, f32x4 c) {
  return __builtin_amdgcn_mfma_f32_16x16x32_f16(a, b, c, 0, 0, 0);
}

#define FMA8(ACC, EI, X, W0, W1)                                    \
  ACC[(EI)*8+0] += (X) * (W0).x; ACC[(EI)*8+1] += (X) * (W0).y;     \
  ACC[(EI)*8+2] += (X) * (W0).z; ACC[(EI)*8+3] += (X) * (W0).w;     \
  ACC[(EI)*8+4] += (X) * (W1).x; ACC[(EI)*8+5] += (X) * (W1).y;     \
  ACC[(EI)*8+6] += (X) * (W1).z; ACC[(EI)*8+7] += (X) * (W1).w;

// ---------------------------------------------------------------------------
// qterm[g][o] = b[o] + qs[g] @ W[512:768] + qr[g] @ W[768:1024]
// ---------------------------------------------------------------------------
__global__ __launch_bounds__(512)
void qterm_kernel(const float* __restrict__ qse, const float* __restrict__ qre,
                  const float* __restrict__ Wl, const float* __restrict__ bl,
                  const float* __restrict__ Wr, const float* __restrict__ br,
                  float* __restrict__ qtl, float* __restrict__ qtr)
{
  const int g = blockIdx.x;
  const int o = threadIdx.x;
  __shared__ float sq[DDIM];
  __shared__ float sr[DDIM];
  if (o < DDIM) sq[o] = qse[(size_t)g * DDIM + o];
  else          sr[o - DDIM] = qre[(size_t)g * DDIM + (o - DDIM)];
  __syncthreads();
  float al = bl[o], ar = br[o];
  for (int k = 0; k < DDIM; ++k) {
    float a = sq[k], b = sr[k];
    al += a * Wl[(size_t)(512 + k) * NH + o] + b * Wl[(size_t)(768 + k) * NH + o];
    ar += a * Wr[(size_t)(512 + k) * NH + o] + b * Wr[(size_t)(768 + k) * NH + o];
  }
  qtl[(size_t)g * NH + o] = al;
  qtr[(size_t)g * NH + o] = ar;
}

// ---------------------------------------------------------------------------
// fp32 score kernel (edges1 / pass1).
// 32 edges/block, 256 threads, 4 waves x 8 edges.
// Lane o-mapping: outs {4*lane..4*lane+3} and {256+4*lane..+3}.
// Weights staged via LDS in 16-row chunks, shared by all waves.
// ---------------------------------------------------------------------------
__global__ __launch_bounds__(256, 2)
void score_kernel(const int* __restrict__ edges,
                  const float* __restrict__ emb,
                  const float* __restrict__ rel,
                  const float* __restrict__ Wl,
                  const float* __restrict__ Wr,
                  const float* __restrict__ Wc,
                  const float* __restrict__ bc,
                  const float* __restrict__ qtl,
                  const float* __restrict__ qtr,
                  float* __restrict__ logits)
{
  __shared__ float wbuf[16 * 512];   // 32 KB weight chunk
  __shared__ float xs[64][36];       // k-major gathered X chunk
  __shared__ float rs[16][36];       // k-major leaky(r) chunk (C phase)
  __shared__ int   meta[32][3];

  const int tid  = threadIdx.x;
  const int lane = tid & 63;
  const int wid  = tid >> 6;
  const int eb   = wid * 8;          // this wave's edge base
  const int e0   = blockIdx.x * TE;
  const int le   = tid >> 3, ls = tid & 7;

  if (tid < TE) {
    const int* er = edges + (size_t)(e0 + tid) * 8;
    meta[tid][0] = er[6]; meta[tid][1] = er[7]; meta[tid][2] = er[0];
  }

  auto stage_w = [&](const float* Wsrc, int k0) {
    const int r = tid >> 4, c0 = (tid & 15) * 32;
    const float* src = Wsrc + (size_t)(k0 + r) * NH + c0;
    float* dst = wbuf + r * 512 + c0;
#pragma unroll
    for (int q = 0; q < 8; ++q) {
      int cc = ((q + (tid & 15)) & 7) * 4;       // staggered to spread banks
      *(float4*)(dst + cc) = *(const float4*)(src + cc);
    }
  };

  auto stage_x = [&](const float* emb_, int metacol, int c64) {
    int kb = c64 * 64;
    const float* src;
    if (kb < 256) src = emb_ + (size_t)meta[le][metacol] * DDIM + kb;
    else          src = rel + (size_t)(e0 + le) * DDIM + (kb - 256);
    float4 a = *(const float4*)(src + ls * 8);
    float4 b = *(const float4*)(src + ls * 8 + 4);
    float v[8] = {a.x, a.y, a.z, a.w, b.x, b.y, b.z, b.w};
#pragma unroll
    for (int q = 0; q < 8; ++q) xs[ls * 8 + q][le] = v[q];
  };

  auto fma16f = [&](float* acc, const float (*xp)[36], int xoff) {
#pragma unroll 2
    for (int kk = 0; kk < 16; ++kk) {
      const float* wr0 = wbuf + kk * 512 + lane * 4;
      float4 w0 = *(const float4*)wr0;
      float4 w1 = *(const float4*)(wr0 + 256);
      float4 x0 = *(const float4*)(&xp[xoff + kk][eb]);
      float4 x1 = *(const float4*)(&xp[xoff + kk][eb + 4]);
      float xv[8] = {x0.x, x0.y, x0.z, x0.w, x1.x, x1.y, x1.z, x1.w};
#pragma unroll
      for (int ei = 0; ei < 8; ++ei) {
        FMA8(acc, ei, xv[ei], w0, w1)
      }
    }
  };

  // ---------------- R phase ----------------
  float accR[64];
#pragma unroll
  for (int q = 0; q < 64; ++q) accR[q] = 0.0f;
  for (int c = 0; c < 32; ++c) {
    __syncthreads();
    stage_w(Wr, c * 16);
    if ((c & 3) == 0) stage_x(emb, 1, c >> 2);
    __syncthreads();
    fma16f(accR, xs, (c & 3) * 16);
  }
#pragma unroll
  for (int ei = 0; ei < 8; ++ei) {
    const float* q = qtr + (size_t)meta[eb + ei][2] * NH;
    float4 q0 = *(const float4*)(q + lane * 4);
    float4 q1 = *(const float4*)(q + 256 + lane * 4);
    accR[ei*8+0] = lrelu(accR[ei*8+0] + q0.x);
    accR[ei*8+1] = lrelu(accR[ei*8+1] + q0.y);
    accR[ei*8+2] = lrelu(accR[ei*8+2] + q0.z);
    accR[ei*8+3] = lrelu(accR[ei*8+3] + q0.w);
    accR[ei*8+4] = lrelu(accR[ei*8+4] + q1.x);
    accR[ei*8+5] = lrelu(accR[ei*8+5] + q1.y);
    accR[ei*8+6] = lrelu(accR[ei*8+6] + q1.z);
    accR[ei*8+7] = lrelu(accR[ei*8+7] + q1.w);
  }

  // ---------------- C phase: r_out = leaky_r @ Wc + bc ----------------
  // HALF must be a LITERAL so accR indices stay compile-time (v3 scratch bug).
  float accC[64];
  {
    float4 b0 = *(const float4*)(bc + lane * 4);
    float4 b1 = *(const float4*)(bc + 256 + lane * 4);
#pragma unroll
    for (int ei = 0; ei < 8; ++ei) {
      accC[ei*8+0] = b0.x; accC[ei*8+1] = b0.y; accC[ei*8+2] = b0.z; accC[ei*8+3] = b0.w;
      accC[ei*8+4] = b1.x; accC[ei*8+5] = b1.y; accC[ei*8+6] = b1.z; accC[ei*8+7] = b1.w;
    }
  }

#define CPHASE_HALF(HALF)                                                     \
  for (int cc = 0; cc < 16; ++cc) {                                           \
    __syncthreads();                                                          \
    stage_w(Wc, (HALF * 16 + cc) * 16);                                       \
    if ((lane >> 2) == cc) {                                                  \
      const int d = lane & 3;                                                 \
      _Pragma("unroll")                                                       \
      for (int ei = 0; ei < 8; ++ei) {                                        \
        rs[d * 4 + 0][eb + ei] = accR[ei * 8 + HALF * 4 + 0];                 \
        rs[d * 4 + 1][eb + ei] = accR[ei * 8 + HALF * 4 + 1];                 \
        rs[d * 4 + 2][eb + ei] = accR[ei * 8 + HALF * 4 + 2];                 \
        rs[d * 4 + 3][eb + ei] = accR[ei * 8 + HALF * 4 + 3];                 \
      }                                                                       \
    }                                                                         \
    __syncthreads();                                                          \
    fma16f(accC, rs, 0);                                                      \
  }

  CPHASE_HALF(0)
  CPHASE_HALF(1)
#undef CPHASE_HALF

  // ---------------- L phase ----------------
  float accL[64];
#pragma unroll
  for (int q = 0; q < 64; ++q) accL[q] = 0.0f;
  for (int c = 0; c < 32; ++c) {
    __syncthreads();
    stage_w(Wl, c * 16);
    if ((c & 3) == 0) stage_x(emb, 0, c >> 2);
    __syncthreads();
    fma16f(accL, xs, (c & 3) * 16);
  }
#pragma unroll
  for (int ei = 0; ei < 8; ++ei) {
    const float* q = qtl + (size_t)meta[eb + ei][2] * NH;
    float4 q0 = *(const float4*)(q + lane * 4);
    float4 q1 = *(const float4*)(q + 256 + lane * 4);
    accL[ei*8+0] = lrelu(accL[ei*8+0] + q0.x);
    accL[ei*8+1] = lrelu(accL[ei*8+1] + q0.y);
    accL[ei*8+2] = lrelu(accL[ei*8+2] + q0.z);
    accL[ei*8+3] = lrelu(accL[ei*8+3] + q0.w);
    accL[ei*8+4] = lrelu(accL[ei*8+4] + q1.x);
    accL[ei*8+5] = lrelu(accL[ei*8+5] + q1.y);
    accL[ei*8+6] = lrelu(accL[ei*8+6] + q1.z);
    accL[ei*8+7] = lrelu(accL[ei*8+7] + q1.w);
  }

  // ---------------- dot + wave reduce ----------------
  float p[8];
#pragma unroll
  for (int ei = 0; ei < 8; ++ei) {
    float s = 0.0f;
#pragma unroll
    for (int oi = 0; oi < 8; ++oi) s += accL[ei * 8 + oi] * accC[ei * 8 + oi];
    p[ei] = s;
  }
#pragma unroll
  for (int off = 1; off < 64; off <<= 1) {
#pragma unroll
    for (int ei = 0; ei < 8; ++ei) p[ei] += __shfl_xor(p[ei], off);
  }
#pragma unroll
  for (int ei = 0; ei < 8; ++ei)
    if (lane == ei) logits[e0 + eb + ei] = p[ei];
}

// ---------------------------------------------------------------------------
// weight prep: Wt{H,L}[o][k] = splitf16(W[k][o]) for Wl[0:512], Wr[0:512], Wc
// ---------------------------------------------------------------------------
__global__ __launch_bounds__(256)
void wprep_kernel(const float* __restrict__ Wl, const float* __restrict__ Wr,
                  const float* __restrict__ Wc,
                  unsigned short* __restrict__ WltH, unsigned short* __restrict__ WltL,
                  unsigned short* __restrict__ WrtH, unsigned short* __restrict__ WrtL,
                  unsigned short* __restrict__ WctH, unsigned short* __restrict__ WctL)
{
  __shared__ float shv[32][33];
  const int mtx = blockIdx.y;
  const int ti = blockIdx.x >> 4;     // k tile
  const int tj = blockIdx.x & 15;     // o tile
  const float* W = mtx == 0 ? Wl : (mtx == 1 ? Wr : Wc);
  unsigned short* OH = mtx == 0 ? WltH : (mtx == 1 ? WrtH : WctH);
  unsigned short* OL = mtx == 0 ? WltL : (mtx == 1 ? WrtL : WctL);
  const int t = threadIdx.x;
  const int r = t >> 3, c4 = (t & 7) * 4;
  *(float4*)&shv[r][c4] = *(const float4*)(W + (size_t)(ti * 32 + r) * 512 + tj * 32 + c4);
  __syncthreads();
  unsigned short h[4], l[4];
#pragma unroll
  for (int q = 0; q < 4; ++q) splitf(shv[c4 + q][r], h[q], l[q]);
  const size_t off = (size_t)(tj * 32 + r) * 512 + ti * 32 + c4;
  *(uint2*)(OH + off) = make_uint2((unsigned)h[0] | ((unsigned)h[1] << 16),
                                   (unsigned)h[2] | ((unsigned)h[3] << 16));
  *(uint2*)(OL + off) = make_uint2((unsigned)l[0] | ((unsigned)l[1] << 16),
                                   (unsigned)l[2] | ((unsigned)l[3] << 16));
}

// ---------------------------------------------------------------------------
// split-f16 MFMA GEMM, 128x128 tile, 4 waves (2x2), 4x4 16x16x32 tiles/wave.
// MODE 0: A = gather([emb1[j]|rel0]) split on the fly; epi: leaky(+qtr) -> packed Lr
// MODE 1: A = unpack(LrPack);                          epi: +bc -> Rout f32
// MODE 2: A = gather([emb1[i]|rel0]);                  epi: leaky(+qtl), dot with
//         Rout, 16-lane reduce, atomicAdd -> logits0
// ---------------------------------------------------------------------------
template<int MODE>
__global__ __launch_bounds__(256)
void gemm_kernel(const int* __restrict__ edges, int ebase,
                 const float* __restrict__ emb, const float* __restrict__ rel,
                 const unsigned* __restrict__ Apack,
                 const unsigned short* __restrict__ BtH,
                 const unsigned short* __restrict__ BtL,
                 const float* __restrict__ qt, const float* __restrict__ bcv,
                 unsigned* __restrict__ OutU,
                 const float* __restrict__ Rin,
                 float* __restrict__ logits)
{
  __shared__ int sidx[128];
  __shared__ int sgrp[128];
  __shared__ unsigned bounce[64][132];

  const int tid  = threadIdx.x;
  const int lane = tid & 63;
  const int wid  = tid >> 6;
  const int wm = wid >> 1, wn = wid & 1;
  const int mb = blockIdx.x >> 2, nb = blockIdx.x & 3;
  const int rb = mb * 128;                 // chunk-local row base
  const int arow = lane & 15;
  const int kgrp = (lane >> 4) * 8;
  const int col0 = nb * 128 + wn * 64;
  const int row0 = wm * 64;

  if (MODE != 1) {
    if (tid < 128) {
      const int* er = edges + (size_t)(ebase + rb + tid) * 8;
      sidx[tid] = er[MODE == 0 ? 7 : 6];
      sgrp[tid] = er[0];
    }
    __syncthreads();
  }

  f32x4 acc[4][4];
#pragma unroll
  for (int a = 0; a < 4; ++a)
#pragma unroll
    for (int b = 0; b < 4; ++b) acc[a][b] = (f32x4)0.0f;

  for (int ks = 0; ks < 16; ++ks) {
    const int k0 = ks * 32 + kgrp;
    h8v ah[4], al[4], bh[4], bl[4];
#pragma unroll
    for (int nt = 0; nt < 4; ++nt) {
      const size_t boff = (size_t)(col0 + nt * 16 + arow) * 512 + k0;
      bh[nt] = *(const h8v*)(BtH + boff);
      bl[nt] = *(const h8v*)(BtL + boff);
    }
#pragma unroll
    for (int mt = 0; mt < 4; ++mt) {
      const int rl = row0 + mt * 16 + arow;
      h8v h, l;
      if (MODE == 1) {
        const unsigned* ap = Apack + (size_t)(rb + rl) * 512 + k0;
        uint4 p0 = *(const uint4*)ap;
        uint4 p1 = *(const uint4*)(ap + 4);
        unsigned u[8] = {p0.x, p0.y, p0.z, p0.w, p1.x, p1.y, p1.z, p1.w};
        i4v hv, lv;
#pragma unroll
        for (int d = 0; d < 4; ++d) {
          hv[d] = (int)((u[2*d] >> 16) | (u[2*d+1] & 0xffff0000u));
          lv[d] = (int)((u[2*d] & 0xffffu) | (u[2*d+1] << 16));
        }
        h = __builtin_bit_cast(h8v, hv);
        l = __builtin_bit_cast(h8v, lv);
      } else {
        const float* src = (k0 < 256)
            ? emb + (size_t)sidx[rl] * DDIM + k0
            : rel + (size_t)(ebase + rb + rl) * DDIM + (k0 - 256);
        float4 f0 = *(const float4*)src;
        float4 f1 = *(const float4*)(src + 4);
        float v[8] = {f0.x, f0.y, f0.z, f0.w, f1.x, f1.y, f1.z, f1.w};
#pragma unroll
        for (int d = 0; d < 8; ++d) {
          _Float16 hh = (_Float16)v[d];
          h[d] = hh;
          l[d] = (_Float16)(v[d] - (float)hh);
        }
      }
      ah[mt] = h; al[mt] = l;
    }
#pragma unroll
    for (int mt = 0; mt < 4; ++mt)
#pragma unroll
      for (int nt = 0; nt < 4; ++nt) {
        acc[mt][nt] = mfma16(ah[mt], bh[nt], acc[mt][nt]);
        acc[mt][nt] = mfma16(ah[mt], bl[nt], acc[mt][nt]);
        acc[mt][nt] = mfma16(al[mt], bh[nt], acc[mt][nt]);
      }
  }

  if (MODE == 2) {
#pragma unroll
    for (int mt = 0; mt < 4; ++mt) {
#pragma unroll
      for (int reg = 0; reg < 4; ++reg) {
        const int rl = row0 + mt * 16 + (lane >> 4) * 4 + reg;
        const int g = sgrp[rl];
        float s = 0.0f;
#pragma unroll
        for (int nt = 0; nt < 4; ++nt) {
          const int c = col0 + nt * 16 + arow;
          float v = lrelu(acc[mt][nt][reg] + qt[(size_t)g * NH + c]);
          s += v * Rin[(size_t)(rb + rl) * 512 + c];
        }
        s += __shfl_xor(s, 1); s += __shfl_xor(s, 2);
        s += __shfl_xor(s, 4); s += __shfl_xor(s, 8);
        if ((lane & 15) == 0)
          atomicAdd(logits + ebase + rb + rl, s);
      }
    }
    return;
  }

  unsigned pk[4][4][4];
#pragma unroll
  for (int mt = 0; mt < 4; ++mt)
#pragma unroll
    for (int nt = 0; nt < 4; ++nt) {
      const int c = col0 + nt * 16 + arow;
#pragma unroll
      for (int reg = 0; reg < 4; ++reg) {
        const int rl = row0 + mt * 16 + (lane >> 4) * 4 + reg;
        float v = acc[mt][nt][reg];
        if (MODE == 0) {
          v = lrelu(v + qt[(size_t)sgrp[rl] * NH + c]);
          pk[mt][nt][reg] = packsplit(v);
        } else {
          pk[mt][nt][reg] = __float_as_uint(v + bcv[c]);
        }
      }
    }
#pragma unroll
  for (int half = 0; half < 2; ++half) {
    __syncthreads();
    if (wm == half) {
#pragma unroll
      for (int mt = 0; mt < 4; ++mt)
#pragma unroll
        for (int nt = 0; nt < 4; ++nt) {
          const int cl = wn * 64 + nt * 16 + arow;
#pragma unroll
          for (int reg = 0; reg < 4; ++reg)
            bounce[mt * 16 + (lane >> 4) * 4 + reg][cl] = pk[mt][nt][reg];
        }
    }
    __syncthreads();
    {
      const int r = tid >> 2, cb = (tid & 3) * 32;
      unsigned* dst = OutU + (size_t)(rb + half * 64 + r) * 512 + nb * 128 + cb;
      const unsigned* s0 = &bounce[r][cb];
#pragma unroll
      for (int q = 0; q < 8; ++q)
        *(uint4*)(dst + q * 4) = *(const uint4*)(s0 + q * 4);
    }
  }
}

// ---------------------------------------------------------------------------
// segment softmax helpers
// ---------------------------------------------------------------------------
__global__ void smax_max_kernel(const int* __restrict__ edges, const float* __restrict__ logits,
                                unsigned* __restrict__ mkey, int E)
{
  int e = blockIdx.x * blockDim.x + threadIdx.x;
  if (e < E) atomicMax(mkey + edges[(size_t)e * 8 + 6], fenc(logits[e]));
}

__global__ void smax_exp_kernel(const int* __restrict__ edges, const float* __restrict__ logits,
                                const unsigned* __restrict__ mkey, float* __restrict__ ssum,
                                float* __restrict__ sm, int E)
{
  int e = blockIdx.x * blockDim.x + threadIdx.x;
  if (e < E) {
    int s = edges[(size_t)e * 8 + 6];
    float ev = expf(logits[e] - fdec(mkey[s]));
    sm[e] = ev;
    atomicAdd(ssum + s, ev);
  }
}

__global__ void smax_norm_kernel(const int* __restrict__ edges, const float* __restrict__ ssum,
                                 float* __restrict__ sm, const float* __restrict__ nscore,
                                 float* __restrict__ ta, int E)
{
  int e = blockIdx.x * blockDim.x + threadIdx.x;
  if (e < E) {
    int s = edges[(size_t)e * 8 + 6];
    float v = sm[e] / ssum[s];
    sm[e] = v;
    if (ta) ta[e] = v * nscore[s];
  }
}

// ---------------------------------------------------------------------------
// per-group top-256 of 1024 (desc value, ties -> low idx), bitonic sort
// ---------------------------------------------------------------------------
__global__ __launch_bounds__(256)
void topk_kernel(const float* __restrict__ ta, const float* __restrict__ sm1,
                 const int* __restrict__ edges1,
                 float* __restrict__ out0, float* __restrict__ out2,
                 float* __restrict__ out3, float* __restrict__ smp,
                 int* __restrict__ prn_i, int* __restrict__ prn_j,
                 int* __restrict__ cnt1)
{
  __shared__ float v[EPG];
  __shared__ int   ix[EPG];
  const int g = blockIdx.x, tid = threadIdx.x;
  for (int t = tid; t < EPG; t += 256) { v[t] = ta[(size_t)g * EPG + t]; ix[t] = t; }
  __syncthreads();
  for (int k = 2; k <= EPG; k <<= 1) {
    for (int j = k >> 1; j > 0; j >>= 1) {
      for (int t = tid; t < EPG; t += 256) {
        int l = t ^ j;
        if (l > t) {
          float va = v[t], vb = v[l];
          int ia = ix[t], ib = ix[l];
          bool aFirst = (va > vb) || (va == vb && ia < ib);
          bool up = ((t & k) == 0);
          bool sw = up ? !aFirst : aFirst;
          if (sw) { v[t] = vb; ix[t] = ib; v[l] = va; ix[l] = ia; }
        }
      }
      __syncthreads();
    }
  }
  const int r = tid;
  const int oi = ix[r];
  const float val = v[r];
  const int orig = g * EPG + oi;
  out3[(size_t)g * KTOP + r] = (float)orig;
  const int* er = edges1 + (size_t)orig * 8;
#pragma unroll
  for (int c = 0; c < 8; ++c)
    out2[((size_t)(g * KTOP + r)) * 8 + c] = (float)er[c];
  const int ii = er[6], jj = er[7];
  const float smv = sm1[orig];
  smp[(size_t)g * KTOP + r] = smv;
  prn_i[(size_t)g * KTOP + r] = ii;
  prn_j[(size_t)g * KTOP + r] = jj;
  atomicAdd(out0 + jj, smv * val);
  atomicAdd(cnt1 + jj, 1);
}

__global__ void scatter_kernel(const int* __restrict__ idx_i, int si,
                               const int* __restrict__ idx_j, int sj,
                               const float* __restrict__ w,
                               const float* __restrict__ semb,
                               float* __restrict__ agg)
{
  const int e = blockIdx.x;
  const int o = threadIdx.x;
  const int i = idx_i[(size_t)e * si];
  const int j = idx_j[(size_t)e * sj];
  atomicAdd(agg + (size_t)j * DDIM + o, w[e] * semb[(size_t)i * DDIM + o]);
}

__global__ void cnt_kernel(const int* __restrict__ idx_j, int sj, int* __restrict__ cnt, int E)
{
  int e = blockIdx.x * blockDim.x + threadIdx.x;
  if (e < E) atomicAdd(cnt + idx_j[(size_t)e * sj], 1);
}

__global__ void combine_kernel(const float* __restrict__ mememb, const int* __restrict__ cnt,
                               float* __restrict__ agg)
{
  size_t id = (size_t)blockIdx.x * 256 + threadIdx.x;
  if (cnt[id >> 8] == 0) agg[id] = mememb[id];
}

// ---------------------------------------------------------------------------
// final: out[r] = leaky( (cnt0[r]>0 ? agg0[r] : emb1[r]) @ Wlin + blin )
// ---------------------------------------------------------------------------
__global__ __launch_bounds__(256, 2)
void final_kernel(const float* __restrict__ emb1, const float* __restrict__ agg0,
                  const int* __restrict__ cnt0, const float* __restrict__ Wlin,
                  const float* __restrict__ blin, float* __restrict__ out)
{
  __shared__ float As[64][68];
  __shared__ int scnt[64];
  const int tid = threadIdx.x;
  const int r0 = blockIdx.x * 64;
  const int ob = (tid & 31) * 8;
  const int rb = (tid >> 5) * 8;
  if (tid < 64) {
    int r = r0 + tid;
    scnt[tid] = (r < NNODES) ? cnt0[r] : 0;
  }
  float acc[64];
  {
    float4 b0 = *(const float4*)(blin + ob);
    float4 b1 = *(const float4*)(blin + ob + 4);
    float bb2[8] = {b0.x, b0.y, b0.z, b0.w, b1.x, b1.y, b1.z, b1.w};
#pragma unroll
    for (int ri = 0; ri < 8; ++ri)
#pragma unroll
      for (int oi = 0; oi < 8; ++oi) acc[ri * 8 + oi] = bb2[oi];
  }
  const int le = tid >> 2, ls = tid & 3;
  for (int c = 0; c < 4; ++c) {
    __syncthreads();
    {
      int r = r0 + le;
      int rc = (r < NNODES) ? r : 0;
      const float* base = (scnt[le] > 0) ? agg0 : emb1;
      const float4* s4 = (const float4*)(base + (size_t)rc * DDIM + c * 64 + ls * 16);
      float4 a0 = s4[0], a1 = s4[1], a2 = s4[2], a3 = s4[3];
      *(float4*)&As[le][ls * 16]      = a0;
      *(float4*)&As[le][ls * 16 + 4]  = a1;
      *(float4*)&As[le][ls * 16 + 8]  = a2;
      *(float4*)&As[le][ls * 16 + 12] = a3;
    }
    __syncthreads();
    const float* wb = Wlin + (size_t)(c * 64) * DDIM + ob;
#pragma unroll 2
    for (int k = 0; k < 64; ++k) {
      float4 w0 = *(const float4*)(wb + (size_t)k * DDIM);
      float4 w1 = *(const float4*)(wb + (size_t)k * DDIM + 4);
#pragma unroll
      for (int ri = 0; ri < 8; ++ri) {
        float x = As[rb + ri][k];
        FMA8(acc, ri, x, w0, w1)
      }
    }
  }
#pragma unroll
  for (int ri = 0; ri < 8; ++ri) {
    int r = r0 + rb + ri;
    if (r < NNODES) {
      float4 o0 = make_float4(lrelu(acc[ri*8+0]), lrelu(acc[ri*8+1]),
                              lrelu(acc[ri*8+2]), lrelu(acc[ri*8+3]));
      float4 o1 = make_float4(lrelu(acc[ri*8+4]), lrelu(acc[ri*8+5]),
                              lrelu(acc[ri*8+6]), lrelu(acc[ri*8+7]));
      *(float4*)(out + (size_t)r * DDIM + ob)     = o0;
      *(float4*)(out + (size_t)r * DDIM + ob + 4) = o1;
    }
  }
}

// ---------------------------------------------------------------------------
extern "C" void kernel_launch(void* const* d_in, const int* in_sizes, int n_in,
                              void* d_out, int out_size, void* d_ws, size_t ws_size,
                              hipStream_t stream)
{
  (void)in_sizes; (void)n_in; (void)out_size;

  const float* node_score = (const float*)d_in[1];
  const int*   edges0 = (const int*)d_in[2];
  const int*   edges1 = (const int*)d_in[3];
  const float* rel0   = (const float*)d_in[4];
  const float* rel1   = (const float*)d_in[5];
  const float* mememb = (const float*)d_in[6];
  const float* qse    = (const float*)d_in[7];
  const float* qre    = (const float*)d_in[8];
  const float* Wl     = (const float*)d_in[9];
  const float* bl     = (const float*)d_in[10];
  const float* Wr     = (const float*)d_in[11];
  const float* br     = (const float*)d_in[12];
  const float* Wc     = (const float*)d_in[13];
  const float* bc     = (const float*)d_in[14];
  const float* Wlin   = (const float*)d_in[15];
  const float* blin   = (const float*)d_in[16];

  float* out0 = (float*)d_out;
  float* out1 = out0 + NNODES;
  float* out2 = out1 + (size_t)NNODES * DDIM;
  float* out3 = out2 + (size_t)NGROUP * KTOP * 8;

  char* wptr = (char*)d_ws;
  auto alloc = [&](size_t bytes) -> char* {
    char* p = wptr;
    wptr += (bytes + 255) & ~(size_t)255;
    return p;
  };
  float*    qtl     = (float*)alloc((size_t)NGROUP * NH * 4);
  float*    qtr     = (float*)alloc((size_t)NGROUP * NH * 4);
  float*    logits1 = (float*)alloc((size_t)E1N * 4);
  float*    sm1     = (float*)alloc((size_t)E1N * 4);
  float*    ta      = (float*)alloc((size_t)E1N * 4);
  float*    logits0 = (float*)alloc((size_t)E0N * 4);
  float*    sm0     = (float*)alloc((size_t)E0N * 4);
  unsigned* mkey    = (unsigned*)alloc((size_t)NNODES * 4);
  float*    ssum    = (float*)alloc((size_t)NNODES * 4);
  int*      cnt1    = (int*)alloc((size_t)NNODES * 4);
  int*      cnt0    = (int*)alloc((size_t)NNODES * 4);
  float*    smp     = (float*)alloc((size_t)NGROUP * KTOP * 4);
  int*      prn_i   = (int*)alloc((size_t)NGROUP * KTOP * 4);
  int*      prn_j   = (int*)alloc((size_t)NGROUP * KTOP * 4);
  float*    agg1    = (float*)alloc((size_t)NNODES * DDIM * 4);   // emb1

  unsigned short* WltH = (unsigned short*)alloc((size_t)512 * 512 * 2);
  unsigned short* WltL = (unsigned short*)alloc((size_t)512 * 512 * 2);
  unsigned short* WrtH = (unsigned short*)alloc((size_t)512 * 512 * 2);
  unsigned short* WrtL = (unsigned short*)alloc((size_t)512 * 512 * 2);
  unsigned short* WctH = (unsigned short*)alloc((size_t)512 * 512 * 2);
  unsigned short* WctL = (unsigned short*)alloc((size_t)512 * 512 * 2);

  // adaptive chunking of the pass-0 GEMM pipeline to fit workspace
  size_t used = (size_t)(wptr - (char*)d_ws);
  int nchunks = 4;
  while (nchunks < 32 && used + 2 * ((size_t)(E0N / nchunks) * 512 * 4 + 256) > ws_size)
    nchunks <<= 1;
  const int CE = E0N / nchunks;
  unsigned* LrPack = (unsigned*)alloc((size_t)CE * 512 * 4);
  float*    Rout   = (float*)alloc((size_t)CE * 512 * 4);

  // ---- pass 1 ----
  (void)hipMemsetAsync(agg1, 0, (size_t)NNODES * DDIM * 4, stream);
  (void)hipMemsetAsync(cnt1, 0, (size_t)NNODES * 4, stream);
  (void)hipMemsetAsync(mkey, 0, (size_t)NNODES * 4, stream);
  (void)hipMemsetAsync(ssum, 0, (size_t)NNODES * 4, stream);
  (void)hipMemsetAsync(out0, 0, (size_t)NNODES * 4, stream);

  qterm_kernel<<<NGROUP, 512, 0, stream>>>(qse, qre, Wl, bl, Wr, br, qtl, qtr);
  {
    dim3 g(256, 3);
    wprep_kernel<<<g, 256, 0, stream>>>(Wl, Wr, Wc, WltH, WltL, WrtH, WrtL, WctH, WctL);
  }
  score_kernel<<<E1N / TE, 256, 0, stream>>>(edges1, mememb, rel1, Wl, Wr, Wc, bc,
                                             qtl, qtr, logits1);
  smax_max_kernel<<<E1N / 256, 256, 0, stream>>>(edges1, logits1, mkey, E1N);
  smax_exp_kernel<<<E1N / 256, 256, 0, stream>>>(edges1, logits1, mkey, ssum, sm1, E1N);
  smax_norm_kernel<<<E1N / 256, 256, 0, stream>>>(edges1, ssum, sm1, node_score, ta, E1N);
  topk_kernel<<<NGROUP, 256, 0, stream>>>(ta, sm1, edges1, out0, out2, out3,
                                          smp, prn_i, prn_j, cnt1);
  scatter_kernel<<<NGROUP * KTOP, 256, 0, stream>>>(prn_i, 1, prn_j, 1, smp, mememb, agg1);
  combine_kernel<<<NNODES, 256, 0, stream>>>(mememb, cnt1, agg1);   // agg1 = emb1

  // ---- pass 0 ----
  (void)hipMemsetAsync(mkey, 0, (size_t)NNODES * 4, stream);
  (void)hipMemsetAsync(ssum, 0, (size_t)NNODES * 4, stream);
  (void)hipMemsetAsync(cnt0, 0, (size_t)NNODES * 4, stream);
  (void)hipMemsetAsync(out1, 0, (size_t)NNODES * DDIM * 4, stream);
  (void)hipMemsetAsync(logits0, 0, (size_t)E0N * 4, stream);

  for (int ch = 0; ch < nchunks; ++ch) {
    const int eb = ch * CE;
    dim3 g((CE / 128) * 4);
    gemm_kernel<0><<<g, 256, 0, stream>>>(edges0, eb, agg1, rel0, nullptr,
                                          WrtH, WrtL, qtr, nullptr,
                                          LrPack, nullptr, nullptr);
    gemm_kernel<1><<<g, 256, 0, stream>>>(edges0, eb, agg1, rel0, LrPack,
                                          WctH, WctL, nullptr, bc,
                                          (unsigned*)Rout, nullptr, nullptr);
    gemm_kernel<2><<<g, 256, 0, stream>>>(edges0, eb, agg1, rel0, nullptr,
                                          WltH, WltL, qtl, nullptr,
                                          nullptr, Rout, logits0);
  }

  smax_max_kernel<<<E0N / 256, 256, 0, stream>>>(edges0, logits0, mkey, E0N);
  smax_exp_kernel<<<E0N / 256, 256, 0, stream>>>(edges0, logits0, mkey, ssum, sm0, E0N);
  smax_norm_kernel<<<E0N / 256, 256, 0, stream>>>(edges0, ssum, sm0, nullptr, nullptr, E0N);
  scatter_kernel<<<E0N, 256, 0, stream>>>(edges0 + 6, 8, edges0 + 7, 8, sm0, agg1, out1);
  cnt_kernel<<<E0N / 256, 256, 0, stream>>>(edges0 + 7, 8, cnt0, E0N);
  final_kernel<<<(NNODES + 63) / 64, 256, 0, stream>>>(agg1, out1, cnt0, Wlin, blin, out1);
}

// Round 5
// 1927.999 us; speedup vs baseline: 1.7106x; 1.4658x over previous
//
#include <hip/hip_runtime.h>
#include <math.h>

// ---------------------------------------------------------------------------
// AttentionFlow v5.
//  Both passes now run the MFMA GEMM pipeline (v4's fp32 score_kernel was
//  structurally capped at 54% VALU / 39% of vector peak; the matrix pipe idle).
//  pass1 (edges1, feeds top-k): SPLIT=1 -> hi/lo _Float16, 3 MFMAs/product,
//    residual ~2e-7 on logits (below fp32 accumulation noise). Deterministic:
//    per-(nb,wn) partials to part[8][E], fixed-order reduce (no fp32 atomics
//    in the top-k-feeding path).
//  pass0 (edges0, continuous outputs, 2% threshold): SPLIT=0 -> plain f16,
//    1 MFMA/product (logit err ~5e-4, 20x margin), Lr stored as f16.
// ---------------------------------------------------------------------------

#define NNODES 100000
#define DDIM   256
#define NH     512
#define NGROUP 64
#define EPG    1024
#define E1N    65536
#define E0N    65536
#define KTOP   256
#define ETOT   65536

typedef __attribute__((ext_vector_type(8))) _Float16 h8v;
typedef __attribute__((ext_vector_type(4))) float f32x4;
typedef __attribute__((ext_vector_type(4))) int i4v;

__device__ __forceinline__ float lrelu(float x) { return x > 0.0f ? x : 0.01f * x; }

__device__ __forceinline__ unsigned fenc(float f) {
  unsigned u = __float_as_uint(f);
  return (u & 0x80000000u) ? ~u : (u | 0x80000000u);
}
__device__ __forceinline__ float fdec(unsigned k) {
  unsigned u = (k & 0x80000000u) ? (k & 0x7FFFFFFFu) : ~k;
  return __uint_as_float(u);
}

__device__ __forceinline__ void splitf(float v, unsigned short& h, unsigned short& l) {
  _Float16 hh = (_Float16)v;
  _Float16 ll = (_Float16)(v - (float)hh);
  h = __builtin_bit_cast(unsigned short, hh);
  l = __builtin_bit_cast(unsigned short, ll);
}

__device__ __forceinline__ unsigned packsplit(float v) {
  unsigned short h, l;
  splitf(v, h, l);
  return ((unsigned)h << 16) | (unsigned)l;
}

__device__ __forceinline__ f32x4 mfma16(h8v a, h8v b, f32x4 c) {
  return __builtin_amdgcn_mfma_f32_16x16x32_f16(a, b, c, 0, 0, 0);
}

#define FMA8(ACC, EI, X, W0, W1)                                    \
  ACC[(EI)*8+0] += (X) * (W0).x; ACC[(EI)*8+1] += (X) * (W0).y;     \
  ACC[(EI)*8+2] += (X) * (W0).z; ACC[(EI)*8+3] += (X) * (W0).w;     \
  ACC[(EI)*8+4] += (X) * (W1).x; ACC[(EI)*8+5] += (X) * (W1).y;     \
  ACC[(EI)*8+6] += (X) * (W1).z; ACC[(EI)*8+7] += (X) * (W1).w;

// ---------------------------------------------------------------------------
// qterm[g][o] = b[o] + qs[g] @ W[512:768] + qr[g] @ W[768:1024]
// ---------------------------------------------------------------------------
__global__ __launch_bounds__(512)
void qterm_kernel(const float* __restrict__ qse, const float* __restrict__ qre,
                  const float* __restrict__ Wl, const float* __restrict__ bl,
                  const float* __restrict__ Wr, const float* __restrict__ br,
                  float* __restrict__ qtl, float* __restrict__ qtr)
{
  const int g = blockIdx.x;
  const int o = threadIdx.x;
  __shared__ float sq[DDIM];
  __shared__ float sr[DDIM];
  if (o < DDIM) sq[o] = qse[(size_t)g * DDIM + o];
  else          sr[o - DDIM] = qre[(size_t)g * DDIM + (o - DDIM)];
  __syncthreads();
  float al = bl[o], ar = br[o];
  for (int k = 0; k < DDIM; ++k) {
    float a = sq[k], b = sr[k];
    al += a * Wl[(size_t)(512 + k) * NH + o] + b * Wl[(size_t)(768 + k) * NH + o];
    ar += a * Wr[(size_t)(512 + k) * NH + o] + b * Wr[(size_t)(768 + k) * NH + o];
  }
  qtl[(size_t)g * NH + o] = al;
  qtr[(size_t)g * NH + o] = ar;
}

// ---------------------------------------------------------------------------
// weight prep: Wt{H,L}[o][k] = splitf16(W[k][o]) for Wl[0:512], Wr[0:512], Wc
// ---------------------------------------------------------------------------
__global__ __launch_bounds__(256)
void wprep_kernel(const float* __restrict__ Wl, const float* __restrict__ Wr,
                  const float* __restrict__ Wc,
                  unsigned short* __restrict__ WltH, unsigned short* __restrict__ WltL,
                  unsigned short* __restrict__ WrtH, unsigned short* __restrict__ WrtL,
                  unsigned short* __restrict__ WctH, unsigned short* __restrict__ WctL)
{
  __shared__ float shv[32][33];
  const int mtx = blockIdx.y;
  const int ti = blockIdx.x >> 4;     // k tile
  const int tj = blockIdx.x & 15;     // o tile
  const float* W = mtx == 0 ? Wl : (mtx == 1 ? Wr : Wc);
  unsigned short* OH = mtx == 0 ? WltH : (mtx == 1 ? WrtH : WctH);
  unsigned short* OL = mtx == 0 ? WltL : (mtx == 1 ? WrtL : WctL);
  const int t = threadIdx.x;
  const int r = t >> 3, c4 = (t & 7) * 4;
  *(float4*)&shv[r][c4] = *(const float4*)(W + (size_t)(ti * 32 + r) * 512 + tj * 32 + c4);
  __syncthreads();
  unsigned short h[4], l[4];
#pragma unroll
  for (int q = 0; q < 4; ++q) splitf(shv[c4 + q][r], h[q], l[q]);
  const size_t off = (size_t)(tj * 32 + r) * 512 + ti * 32 + c4;
  *(uint2*)(OH + off) = make_uint2((unsigned)h[0] | ((unsigned)h[1] << 16),
                                   (unsigned)h[2] | ((unsigned)h[3] << 16));
  *(uint2*)(OL + off) = make_uint2((unsigned)l[0] | ((unsigned)l[1] << 16),
                                   (unsigned)l[2] | ((unsigned)l[3] << 16));
}

// ---------------------------------------------------------------------------
// f16 MFMA GEMM, 128x128 tile, 4 waves (2x2), 4x4 16x16x32 tiles/wave.
// SPLIT=1: hi/lo split, 3 MFMAs/product (pass1, exact-ish). Lr packed u32.
// SPLIT=0: plain f16, 1 MFMA/product (pass0, continuous).  Lr plain f16.
// MODE 0: A = gather([emb[jcol]|rel]); epi: leaky(+qt) -> Lr
// MODE 1: A = Lr;                      epi: +bc -> Rout f32
// MODE 2: A = gather([emb[icol]|rel]); epi: leaky(+qt), dot Rin,
//         16-lane reduce -> part[(nb*2+wn)][edge]   (deterministic)
// ---------------------------------------------------------------------------
template<int MODE, int SPLIT>
__global__ __launch_bounds__(256)
void gemm_kernel(const int* __restrict__ edges, int ebase,
                 const float* __restrict__ emb, const float* __restrict__ rel,
                 const unsigned* __restrict__ Apack,
                 const unsigned short* __restrict__ BtH,
                 const unsigned short* __restrict__ BtL,
                 const float* __restrict__ qt, const float* __restrict__ bcv,
                 unsigned* __restrict__ OutU,
                 const float* __restrict__ Rin,
                 float* __restrict__ part)
{
  __shared__ int sidx[128];
  __shared__ int sgrp[128];
  __shared__ unsigned bounce[64][132];

  const int tid  = threadIdx.x;
  const int lane = tid & 63;
  const int wid  = tid >> 6;
  const int wm = wid >> 1, wn = wid & 1;
  const int mb = blockIdx.x >> 2, nb = blockIdx.x & 3;
  const int rb = mb * 128;                 // chunk-local row base
  const int arow = lane & 15;
  const int kgrp = (lane >> 4) * 8;
  const int col0 = nb * 128 + wn * 64;
  const int row0 = wm * 64;

  if (MODE != 1) {
    if (tid < 128) {
      const int* er = edges + (size_t)(ebase + rb + tid) * 8;
      sidx[tid] = er[MODE == 0 ? 7 : 6];
      sgrp[tid] = er[0];
    }
    __syncthreads();
  }

  f32x4 acc[4][4];
#pragma unroll
  for (int a = 0; a < 4; ++a)
#pragma unroll
    for (int b = 0; b < 4; ++b) acc[a][b] = (f32x4)0.0f;

  for (int ks = 0; ks < 16; ++ks) {
    const int k0 = ks * 32 + kgrp;
    h8v ah[4], al[4], bh[4], bl[4];
#pragma unroll
    for (int nt = 0; nt < 4; ++nt) {
      const size_t boff = (size_t)(col0 + nt * 16 + arow) * 512 + k0;
      bh[nt] = *(const h8v*)(BtH + boff);
      if (SPLIT) bl[nt] = *(const h8v*)(BtL + boff);
    }
#pragma unroll
    for (int mt = 0; mt < 4; ++mt) {
      const int rl = row0 + mt * 16 + arow;
      h8v h, l;
      if (MODE == 1) {
        if (SPLIT) {
          const unsigned* ap = Apack + (size_t)(rb + rl) * 512 + k0;
          uint4 p0 = *(const uint4*)ap;
          uint4 p1 = *(const uint4*)(ap + 4);
          unsigned u[8] = {p0.x, p0.y, p0.z, p0.w, p1.x, p1.y, p1.z, p1.w};
          i4v hv, lv;
#pragma unroll
          for (int d = 0; d < 4; ++d) {
            hv[d] = (int)((u[2*d] >> 16) | (u[2*d+1] & 0xffff0000u));
            lv[d] = (int)((u[2*d] & 0xffffu) | (u[2*d+1] << 16));
          }
          h = __builtin_bit_cast(h8v, hv);
          l = __builtin_bit_cast(h8v, lv);
        } else {
          h = *(const h8v*)((const unsigned short*)Apack + (size_t)(rb + rl) * 512 + k0);
        }
      } else {
        const float* src = (k0 < 256)
            ? emb + (size_t)sidx[rl] * DDIM + k0
            : rel + (size_t)(ebase + rb + rl) * DDIM + (k0 - 256);
        float4 f0 = *(const float4*)src;
        float4 f1 = *(const float4*)(src + 4);
        float v[8] = {f0.x, f0.y, f0.z, f0.w, f1.x, f1.y, f1.z, f1.w};
#pragma unroll
        for (int d = 0; d < 8; ++d) {
          _Float16 hh = (_Float16)v[d];
          h[d] = hh;
          if (SPLIT) l[d] = (_Float16)(v[d] - (float)hh);
        }
      }
      ah[mt] = h;
      if (SPLIT) al[mt] = l;
    }
#pragma unroll
    for (int mt = 0; mt < 4; ++mt)
#pragma unroll
      for (int nt = 0; nt < 4; ++nt) {
        acc[mt][nt] = mfma16(ah[mt], bh[nt], acc[mt][nt]);
        if (SPLIT) {
          acc[mt][nt] = mfma16(ah[mt], bl[nt], acc[mt][nt]);
          acc[mt][nt] = mfma16(al[mt], bh[nt], acc[mt][nt]);
        }
      }
  }

  if (MODE == 2) {
#pragma unroll
    for (int mt = 0; mt < 4; ++mt) {
#pragma unroll
      for (int reg = 0; reg < 4; ++reg) {
        const int rl = row0 + mt * 16 + (lane >> 4) * 4 + reg;
        const int g = sgrp[rl];
        float s = 0.0f;
#pragma unroll
        for (int nt = 0; nt < 4; ++nt) {
          const int c = col0 + nt * 16 + arow;
          float v = lrelu(acc[mt][nt][reg] + qt[(size_t)g * NH + c]);
          s += v * Rin[(size_t)(rb + rl) * 512 + c];
        }
        s += __shfl_xor(s, 1); s += __shfl_xor(s, 2);
        s += __shfl_xor(s, 4); s += __shfl_xor(s, 8);
        if ((lane & 15) == 0)
          part[(size_t)(nb * 2 + wn) * ETOT + ebase + rb + rl] = s;
      }
    }
    return;
  }

  unsigned pk[4][4][4];
#pragma unroll
  for (int mt = 0; mt < 4; ++mt)
#pragma unroll
    for (int nt = 0; nt < 4; ++nt) {
      const int c = col0 + nt * 16 + arow;
#pragma unroll
      for (int reg = 0; reg < 4; ++reg) {
        const int rl = row0 + mt * 16 + (lane >> 4) * 4 + reg;
        float v = acc[mt][nt][reg];
        if (MODE == 0) {
          v = lrelu(v + qt[(size_t)sgrp[rl] * NH + c]);
          if (SPLIT) pk[mt][nt][reg] = packsplit(v);
          else pk[mt][nt][reg] =
              (unsigned)__builtin_bit_cast(unsigned short, (_Float16)v);
        } else {
          pk[mt][nt][reg] = __float_as_uint(v + bcv[c]);
        }
      }
    }
#pragma unroll
  for (int half = 0; half < 2; ++half) {
    __syncthreads();
    if (wm == half) {
#pragma unroll
      for (int mt = 0; mt < 4; ++mt)
#pragma unroll
        for (int nt = 0; nt < 4; ++nt) {
          const int cl = wn * 64 + nt * 16 + arow;
#pragma unroll
          for (int reg = 0; reg < 4; ++reg)
            bounce[mt * 16 + (lane >> 4) * 4 + reg][cl] = pk[mt][nt][reg];
        }
    }
    __syncthreads();
    if (MODE == 0 && SPLIT == 0) {
      // pack lo16 pairs -> f16 store (Lr16[row][512])
      const int r = tid >> 2, cb = (tid & 3) * 32;
      unsigned short* dst = (unsigned short*)OutU +
          (size_t)(rb + half * 64 + r) * 512 + nb * 128 + cb;
      unsigned pkk[16];
#pragma unroll
      for (int q = 0; q < 16; ++q) {
        unsigned a = bounce[r][cb + 2 * q], b = bounce[r][cb + 2 * q + 1];
        pkk[q] = (a & 0xffffu) | (b << 16);
      }
#pragma unroll
      for (int q = 0; q < 4; ++q)
        *(uint4*)(dst + q * 16) = *(uint4*)&pkk[q * 4];
    } else {
      const int r = tid >> 2, cb = (tid & 3) * 32;
      unsigned* dst = OutU + (size_t)(rb + half * 64 + r) * 512 + nb * 128 + cb;
      const unsigned* s0 = &bounce[r][cb];
#pragma unroll
      for (int q = 0; q < 8; ++q)
        *(uint4*)(dst + q * 4) = *(const uint4*)(s0 + q * 4);
    }
  }
}

// logits[e] = sum_{p<8} part[p][e]   (fixed order -> deterministic)
__global__ void reduce8_kernel(const float* __restrict__ part,
                               float* __restrict__ logits, int E)
{
  int e = blockIdx.x * blockDim.x + threadIdx.x;
  if (e < E) {
    float s = 0.0f;
#pragma unroll
    for (int p = 0; p < 8; ++p) s += part[(size_t)p * ETOT + e];
    logits[e] = s;
  }
}

// ---------------------------------------------------------------------------
// segment softmax helpers
// ---------------------------------------------------------------------------
__global__ void smax_max_kernel(const int* __restrict__ edges, const float* __restrict__ logits,
                                unsigned* __restrict__ mkey, int E)
{
  int e = blockIdx.x * blockDim.x + threadIdx.x;
  if (e < E) atomicMax(mkey + edges[(size_t)e * 8 + 6], fenc(logits[e]));
}

__global__ void smax_exp_kernel(const int* __restrict__ edges, const float* __restrict__ logits,
                                const unsigned* __restrict__ mkey, float* __restrict__ ssum,
                                float* __restrict__ sm, int E)
{
  int e = blockIdx.x * blockDim.x + threadIdx.x;
  if (e < E) {
    int s = edges[(size_t)e * 8 + 6];
    float ev = expf(logits[e] - fdec(mkey[s]));
    sm[e] = ev;
    atomicAdd(ssum + s, ev);
  }
}

__global__ void smax_norm_kernel(const int* __restrict__ edges, const float* __restrict__ ssum,
                                 float* __restrict__ sm, const float* __restrict__ nscore,
                                 float* __restrict__ ta, int E)
{
  int e = blockIdx.x * blockDim.x + threadIdx.x;
  if (e < E) {
    int s = edges[(size_t)e * 8 + 6];
    float v = sm[e] / ssum[s];
    sm[e] = v;
    if (ta) ta[e] = v * nscore[s];
  }
}

// ---------------------------------------------------------------------------
// per-group top-256 of 1024 (desc value, ties -> low idx), bitonic sort
// ---------------------------------------------------------------------------
__global__ __launch_bounds__(256)
void topk_kernel(const float* __restrict__ ta, const float* __restrict__ sm1,
                 const int* __restrict__ edges1,
                 float* __restrict__ out0, float* __restrict__ out2,
                 float* __restrict__ out3, float* __restrict__ smp,
                 int* __restrict__ prn_i, int* __restrict__ prn_j,
                 int* __restrict__ cnt1)
{
  __shared__ float v[EPG];
  __shared__ int   ix[EPG];
  const int g = blockIdx.x, tid = threadIdx.x;
  for (int t = tid; t < EPG; t += 256) { v[t] = ta[(size_t)g * EPG + t]; ix[t] = t; }
  __syncthreads();
  for (int k = 2; k <= EPG; k <<= 1) {
    for (int j = k >> 1; j > 0; j >>= 1) {
      for (int t = tid; t < EPG; t += 256) {
        int l = t ^ j;
        if (l > t) {
          float va = v[t], vb = v[l];
          int ia = ix[t], ib = ix[l];
          bool aFirst = (va > vb) || (va == vb && ia < ib);
          bool up = ((t & k) == 0);
          bool sw = up ? !aFirst : aFirst;
          if (sw) { v[t] = vb; ix[t] = ib; v[l] = va; ix[l] = ia; }
        }
      }
      __syncthreads();
    }
  }
  const int r = tid;
  const int oi = ix[r];
  const float val = v[r];
  const int orig = g * EPG + oi;
  out3[(size_t)g * KTOP + r] = (float)orig;
  const int* er = edges1 + (size_t)orig * 8;
#pragma unroll
  for (int c = 0; c < 8; ++c)
    out2[((size_t)(g * KTOP + r)) * 8 + c] = (float)er[c];
  const int ii = er[6], jj = er[7];
  const float smv = sm1[orig];
  smp[(size_t)g * KTOP + r] = smv;
  prn_i[(size_t)g * KTOP + r] = ii;
  prn_j[(size_t)g * KTOP + r] = jj;
  atomicAdd(out0 + jj, smv * val);
  atomicAdd(cnt1 + jj, 1);
}

__global__ void scatter_kernel(const int* __restrict__ idx_i, int si,
                               const int* __restrict__ idx_j, int sj,
                               const float* __restrict__ w,
                               const float* __restrict__ semb,
                               float* __restrict__ agg)
{
  const int e = blockIdx.x;
  const int o = threadIdx.x;
  const int i = idx_i[(size_t)e * si];
  const int j = idx_j[(size_t)e * sj];
  atomicAdd(agg + (size_t)j * DDIM + o, w[e] * semb[(size_t)i * DDIM + o]);
}

__global__ void cnt_kernel(const int* __restrict__ idx_j, int sj, int* __restrict__ cnt, int E)
{
  int e = blockIdx.x * blockDim.x + threadIdx.x;
  if (e < E) atomicAdd(cnt + idx_j[(size_t)e * sj], 1);
}

__global__ void combine_kernel(const float* __restrict__ mememb, const int* __restrict__ cnt,
                               float* __restrict__ agg)
{
  size_t id = (size_t)blockIdx.x * 256 + threadIdx.x;
  if (cnt[id >> 8] == 0) agg[id] = mememb[id];
}

// ---------------------------------------------------------------------------
// final: out[r] = leaky( (cnt0[r]>0 ? agg0[r] : emb1[r]) @ Wlin + blin )
// ---------------------------------------------------------------------------
__global__ __launch_bounds__(256, 2)
void final_kernel(const float* __restrict__ emb1, const float* __restrict__ agg0,
                  const int* __restrict__ cnt0, const float* __restrict__ Wlin,
                  const float* __restrict__ blin, float* __restrict__ out)
{
  __shared__ float As[64][68];
  __shared__ int scnt[64];
  const int tid = threadIdx.x;
  const int r0 = blockIdx.x * 64;
  const int ob = (tid & 31) * 8;
  const int rb = (tid >> 5) * 8;
  if (tid < 64) {
    int r = r0 + tid;
    scnt[tid] = (r < NNODES) ? cnt0[r] : 0;
  }
  float acc[64];
  {
    float4 b0 = *(const float4*)(blin + ob);
    float4 b1 = *(const float4*)(blin + ob + 4);
    float bb2[8] = {b0.x, b0.y, b0.z, b0.w, b1.x, b1.y, b1.z, b1.w};
#pragma unroll
    for (int ri = 0; ri < 8; ++ri)
#pragma unroll
      for (int oi = 0; oi < 8; ++oi) acc[ri * 8 + oi] = bb2[oi];
  }
  const int le = tid >> 2, ls = tid & 3;
  for (int c = 0; c < 4; ++c) {
    __syncthreads();
    {
      int r = r0 + le;
      int rc = (r < NNODES) ? r : 0;
      const float* base = (scnt[le] > 0) ? agg0 : emb1;
      const float4* s4 = (const float4*)(base + (size_t)rc * DDIM + c * 64 + ls * 16);
      float4 a0 = s4[0], a1 = s4[1], a2 = s4[2], a3 = s4[3];
      *(float4*)&As[le][ls * 16]      = a0;
      *(float4*)&As[le][ls * 16 + 4]  = a1;
      *(float4*)&As[le][ls * 16 + 8]  = a2;
      *(float4*)&As[le][ls * 16 + 12] = a3;
    }
    __syncthreads();
    const float* wb = Wlin + (size_t)(c * 64) * DDIM + ob;
#pragma unroll 2
    for (int k = 0; k < 64; ++k) {
      float4 w0 = *(const float4*)(wb + (size_t)k * DDIM);
      float4 w1 = *(const float4*)(wb + (size_t)k * DDIM + 4);
#pragma unroll
      for (int ri = 0; ri < 8; ++ri) {
        float x = As[rb + ri][k];
        FMA8(acc, ri, x, w0, w1)
      }
    }
  }
#pragma unroll
  for (int ri = 0; ri < 8; ++ri) {
    int r = r0 + rb + ri;
    if (r < NNODES) {
      float4 o0 = make_float4(lrelu(acc[ri*8+0]), lrelu(acc[ri*8+1]),
                              lrelu(acc[ri*8+2]), lrelu(acc[ri*8+3]));
      float4 o1 = make_float4(lrelu(acc[ri*8+4]), lrelu(acc[ri*8+5]),
                              lrelu(acc[ri*8+6]), lrelu(acc[ri*8+7]));
      *(float4*)(out + (size_t)r * DDIM + ob)     = o0;
      *(float4*)(out + (size_t)r * DDIM + ob + 4) = o1;
    }
  }
}

// ---------------------------------------------------------------------------
extern "C" void kernel_launch(void* const* d_in, const int* in_sizes, int n_in,
                              void* d_out, int out_size, void* d_ws, size_t ws_size,
                              hipStream_t stream)
{
  (void)in_sizes; (void)n_in; (void)out_size;

  const float* node_score = (const float*)d_in[1];
  const int*   edges0 = (const int*)d_in[2];
  const int*   edges1 = (const int*)d_in[3];
  const float* rel0   = (const float*)d_in[4];
  const float* rel1   = (const float*)d_in[5];
  const float* mememb = (const float*)d_in[6];
  const float* qse    = (const float*)d_in[7];
  const float* qre    = (const float*)d_in[8];
  const float* Wl     = (const float*)d_in[9];
  const float* bl     = (const float*)d_in[10];
  const float* Wr     = (const float*)d_in[11];
  const float* br     = (const float*)d_in[12];
  const float* Wc     = (const float*)d_in[13];
  const float* bc     = (const float*)d_in[14];
  const float* Wlin   = (const float*)d_in[15];
  const float* blin   = (const float*)d_in[16];

  float* out0 = (float*)d_out;
  float* out1 = out0 + NNODES;
  float* out2 = out1 + (size_t)NNODES * DDIM;
  float* out3 = out2 + (size_t)NGROUP * KTOP * 8;

  char* wptr = (char*)d_ws;
  auto alloc = [&](size_t bytes) -> char* {
    char* p = wptr;
    wptr += (bytes + 255) & ~(size_t)255;
    return p;
  };
  float*    qtl     = (float*)alloc((size_t)NGROUP * NH * 4);
  float*    qtr     = (float*)alloc((size_t)NGROUP * NH * 4);
  float*    logits1 = (float*)alloc((size_t)E1N * 4);
  float*    sm1     = (float*)alloc((size_t)E1N * 4);
  float*    ta      = (float*)alloc((size_t)E1N * 4);
  float*    logits0 = (float*)alloc((size_t)E0N * 4);
  float*    sm0     = (float*)alloc((size_t)E0N * 4);
  unsigned* mkey    = (unsigned*)alloc((size_t)NNODES * 4);
  float*    ssum    = (float*)alloc((size_t)NNODES * 4);
  int*      cnt1    = (int*)alloc((size_t)NNODES * 4);
  int*      cnt0    = (int*)alloc((size_t)NNODES * 4);
  float*    smp     = (float*)alloc((size_t)NGROUP * KTOP * 4);
  int*      prn_i   = (int*)alloc((size_t)NGROUP * KTOP * 4);
  int*      prn_j   = (int*)alloc((size_t)NGROUP * KTOP * 4);
  float*    part    = (float*)alloc((size_t)8 * ETOT * 4);        // 2 MB
  float*    agg1    = (float*)alloc((size_t)NNODES * DDIM * 4);   // emb1

  unsigned short* WltH = (unsigned short*)alloc((size_t)512 * 512 * 2);
  unsigned short* WltL = (unsigned short*)alloc((size_t)512 * 512 * 2);
  unsigned short* WrtH = (unsigned short*)alloc((size_t)512 * 512 * 2);
  unsigned short* WrtL = (unsigned short*)alloc((size_t)512 * 512 * 2);
  unsigned short* WctH = (unsigned short*)alloc((size_t)512 * 512 * 2);
  unsigned short* WctL = (unsigned short*)alloc((size_t)512 * 512 * 2);

  // adaptive chunking of the GEMM pipeline to fit workspace
  size_t used = (size_t)(wptr - (char*)d_ws);
  int nchunks = 4;
  while (nchunks < 32 && used + 2 * ((size_t)(ETOT / nchunks) * 512 * 4 + 256) > ws_size)
    nchunks <<= 1;
  const int CE = ETOT / nchunks;
  unsigned* Lr   = (unsigned*)alloc((size_t)CE * 512 * 4);  // u32 pack / f16 (reused)
  float*    Rout = (float*)alloc((size_t)CE * 512 * 4);

  // ---- pass 1 prep ----
  (void)hipMemsetAsync(agg1, 0, (size_t)NNODES * DDIM * 4, stream);
  (void)hipMemsetAsync(cnt1, 0, (size_t)NNODES * 4, stream);
  (void)hipMemsetAsync(mkey, 0, (size_t)NNODES * 4, stream);
  (void)hipMemsetAsync(ssum, 0, (size_t)NNODES * 4, stream);
  (void)hipMemsetAsync(out0, 0, (size_t)NNODES * 4, stream);

  qterm_kernel<<<NGROUP, 512, 0, stream>>>(qse, qre, Wl, bl, Wr, br, qtl, qtr);
  {
    dim3 g(256, 3);
    wprep_kernel<<<g, 256, 0, stream>>>(Wl, Wr, Wc, WltH, WltL, WrtH, WrtL, WctH, WctL);
  }

  // ---- pass 1: SPLIT=1 GEMM trio (exact-ish logits for top-k) ----
  for (int ch = 0; ch < nchunks; ++ch) {
    const int eb = ch * CE;
    dim3 g((CE / 128) * 4);
    gemm_kernel<0,1><<<g, 256, 0, stream>>>(edges1, eb, mememb, rel1, nullptr,
                                            WrtH, WrtL, qtr, nullptr,
                                            Lr, nullptr, nullptr);
    gemm_kernel<1,1><<<g, 256, 0, stream>>>(edges1, eb, mememb, rel1, Lr,
                                            WctH, WctL, nullptr, bc,
                                            (unsigned*)Rout, nullptr, nullptr);
    gemm_kernel<2,1><<<g, 256, 0, stream>>>(edges1, eb, mememb, rel1, nullptr,
                                            WltH, WltL, qtl, nullptr,
                                            nullptr, Rout, part);
  }
  reduce8_kernel<<<E1N / 256, 256, 0, stream>>>(part, logits1, E1N);

  smax_max_kernel<<<E1N / 256, 256, 0, stream>>>(edges1, logits1, mkey, E1N);
  smax_exp_kernel<<<E1N / 256, 256, 0, stream>>>(edges1, logits1, mkey, ssum, sm1, E1N);
  smax_norm_kernel<<<E1N / 256, 256, 0, stream>>>(edges1, ssum, sm1, node_score, ta, E1N);
  topk_kernel<<<NGROUP, 256, 0, stream>>>(ta, sm1, edges1, out0, out2, out3,
                                          smp, prn_i, prn_j, cnt1);
  scatter_kernel<<<NGROUP * KTOP, 256, 0, stream>>>(prn_i, 1, prn_j, 1, smp, mememb, agg1);
  combine_kernel<<<NNODES, 256, 0, stream>>>(mememb, cnt1, agg1);   // agg1 = emb1

  // ---- pass 0 prep ----
  (void)hipMemsetAsync(mkey, 0, (size_t)NNODES * 4, stream);
  (void)hipMemsetAsync(ssum, 0, (size_t)NNODES * 4, stream);
  (void)hipMemsetAsync(cnt0, 0, (size_t)NNODES * 4, stream);
  (void)hipMemsetAsync(out1, 0, (size_t)NNODES * DDIM * 4, stream);

  // ---- pass 0: SPLIT=0 GEMM trio (continuous outputs, f16 is plenty) ----
  for (int ch = 0; ch < nchunks; ++ch) {
    const int eb = ch * CE;
    dim3 g((CE / 128) * 4);
    gemm_kernel<0,0><<<g, 256, 0, stream>>>(edges0, eb, agg1, rel0, nullptr,
                                            WrtH, WrtL, qtr, nullptr,
                                            Lr, nullptr, nullptr);
    gemm_kernel<1,0><<<g, 256, 0, stream>>>(edges0, eb, agg1, rel0, Lr,
                                            WctH, WctL, nullptr, bc,
                                            (unsigned*)Rout, nullptr, nullptr);
    gemm_kernel<2,0><<<g, 256, 0, stream>>>(edges0, eb, agg1, rel0, nullptr,
                                            WltH, WltL, qtl, nullptr,
                                            nullptr, Rout, part);
  }
  reduce8_kernel<<<E0N / 256, 256, 0, stream>>>(part, logits0, E0N);

  smax_max_kernel<<<E0N / 256, 256, 0, stream>>>(edges0, logits0, mkey, E0N);
  smax_exp_kernel<<<E0N / 256, 256, 0, stream>>>(edges0, logits0, mkey, ssum, sm0, E0N);
  smax_norm_kernel<<<E0N / 256, 256, 0, stream>>>(edges0, ssum, sm0, nullptr, nullptr, E0N);
  scatter_kernel<<<E0N, 256, 0, stream>>>(edges0 + 6, 8, edges0 + 7, 8, sm0, agg1, out1);
  cnt_kernel<<<E0N / 256, 256, 0, stream>>>(edges0 + 7, 8, cnt0, E0N);
  final_kernel<<<(NNODES + 63) / 64, 256, 0, stream>>>(agg1, out1, cnt0, Wlin, blin, out1);
}

// Round 6
// 1786.636 us; speedup vs baseline: 1.8460x; 1.0791x over previous
//
#include <hip/hip_runtime.h>
#include <math.h>

// ---------------------------------------------------------------------------
// AttentionFlow v6.
//  pass1 (edges1, feeds top-k): split-f16 MFMA trio (3 MFMAs/product,
//    residual ~2e-7). Deterministic partials -> fused reduce+segmax.
//  pass0 (edges0, continuous): plain f16 MFMA trio (1 MFMA/product).
//  v6: final_kernel -> f16 MFMA (8-wave, 128 rows x 256 cols per block, no
//    in-place race); nchunks starts at 1 (kills chunk serialization);
//    reduce8+smax_max fused; cnt folded into smax_exp; scatter 4 edges/block.
// ---------------------------------------------------------------------------

#define NNODES 100000
#define DDIM   256
#define NH     512
#define NGROUP 64
#define EPG    1024
#define E1N    65536
#define E0N    65536
#define KTOP   256
#define ETOT   65536

typedef __attribute__((ext_vector_type(8))) _Float16 h8v;
typedef __attribute__((ext_vector_type(4))) float f32x4;
typedef __attribute__((ext_vector_type(4))) int i4v;

__device__ __forceinline__ float lrelu(float x) { return x > 0.0f ? x : 0.01f * x; }

__device__ __forceinline__ unsigned fenc(float f) {
  unsigned u = __float_as_uint(f);
  return (u & 0x80000000u) ? ~u : (u | 0x80000000u);
}
__device__ __forceinline__ float fdec(unsigned k) {
  unsigned u = (k & 0x80000000u) ? (k & 0x7FFFFFFFu) : ~k;
  return __uint_as_float(u);
}

__device__ __forceinline__ void splitf(float v, unsigned short& h, unsigned short& l) {
  _Float16 hh = (_Float16)v;
  _Float16 ll = (_Float16)(v - (float)hh);
  h = __builtin_bit_cast(unsigned short, hh);
  l = __builtin_bit_cast(unsigned short, ll);
}

__device__ __forceinline__ unsigned packsplit(float v) {
  unsigned short h, l;
  splitf(v, h, l);
  return ((unsigned)h << 16) | (unsigned)l;
}

__device__ __forceinline__ f32x4 mfma16(h8v a, h8v b, f32x4 c) {
  return __builtin_amdgcn_mfma_f32_16x16x32_f16(a, b, c, 0, 0, 0);
}

// ---------------------------------------------------------------------------
// qterm[g][o] = b[o] + qs[g] @ W[512:768] + qr[g] @ W[768:1024]
// ---------------------------------------------------------------------------
__global__ __launch_bounds__(512)
void qterm_kernel(const float* __restrict__ qse, const float* __restrict__ qre,
                  const float* __restrict__ Wl, const float* __restrict__ bl,
                  const float* __restrict__ Wr, const float* __restrict__ br,
                  float* __restrict__ qtl, float* __restrict__ qtr)
{
  const int g = blockIdx.x;
  const int o = threadIdx.x;
  __shared__ float sq[DDIM];
  __shared__ float sr[DDIM];
  if (o < DDIM) sq[o] = qse[(size_t)g * DDIM + o];
  else          sr[o - DDIM] = qre[(size_t)g * DDIM + (o - DDIM)];
  __syncthreads();
  float al = bl[o], ar = br[o];
  for (int k = 0; k < DDIM; ++k) {
    float a = sq[k], b = sr[k];
    al += a * Wl[(size_t)(512 + k) * NH + o] + b * Wl[(size_t)(768 + k) * NH + o];
    ar += a * Wr[(size_t)(512 + k) * NH + o] + b * Wr[(size_t)(768 + k) * NH + o];
  }
  qtl[(size_t)g * NH + o] = al;
  qtr[(size_t)g * NH + o] = ar;
}

// ---------------------------------------------------------------------------
// weight prep: Wt{H,L}[o][k] = splitf16(W[k][o]) for Wl[0:512], Wr[0:512], Wc
// ---------------------------------------------------------------------------
__global__ __launch_bounds__(256)
void wprep_kernel(const float* __restrict__ Wl, const float* __restrict__ Wr,
                  const float* __restrict__ Wc,
                  unsigned short* __restrict__ WltH, unsigned short* __restrict__ WltL,
                  unsigned short* __restrict__ WrtH, unsigned short* __restrict__ WrtL,
                  unsigned short* __restrict__ WctH, unsigned short* __restrict__ WctL)
{
  __shared__ float shv[32][33];
  const int mtx = blockIdx.y;
  const int ti = blockIdx.x >> 4;     // k tile
  const int tj = blockIdx.x & 15;     // o tile
  const float* W = mtx == 0 ? Wl : (mtx == 1 ? Wr : Wc);
  unsigned short* OH = mtx == 0 ? WltH : (mtx == 1 ? WrtH : WctH);
  unsigned short* OL = mtx == 0 ? WltL : (mtx == 1 ? WrtL : WctL);
  const int t = threadIdx.x;
  const int r = t >> 3, c4 = (t & 7) * 4;
  *(float4*)&shv[r][c4] = *(const float4*)(W + (size_t)(ti * 32 + r) * 512 + tj * 32 + c4);
  __syncthreads();
  unsigned short h[4], l[4];
#pragma unroll
  for (int q = 0; q < 4; ++q) splitf(shv[c4 + q][r], h[q], l[q]);
  const size_t off = (size_t)(tj * 32 + r) * 512 + ti * 32 + c4;
  *(uint2*)(OH + off) = make_uint2((unsigned)h[0] | ((unsigned)h[1] << 16),
                                   (unsigned)h[2] | ((unsigned)h[3] << 16));
  *(uint2*)(OL + off) = make_uint2((unsigned)l[0] | ((unsigned)l[1] << 16),
                                   (unsigned)l[2] | ((unsigned)l[3] << 16));
}

// WlinT[o][k] = f16(Wlin[k][o]), 256x256, hi only
__global__ __launch_bounds__(256)
void wlinprep_kernel(const float* __restrict__ Wlin, unsigned short* __restrict__ WlinT)
{
  __shared__ float shv[32][33];
  const int ti = blockIdx.x >> 3;    // k tile
  const int tj = blockIdx.x & 7;     // o tile
  const int t = threadIdx.x;
  const int r = t >> 3, c4 = (t & 7) * 4;
  *(float4*)&shv[r][c4] = *(const float4*)(Wlin + (size_t)(ti * 32 + r) * 256 + tj * 32 + c4);
  __syncthreads();
  unsigned short o[4];
#pragma unroll
  for (int q = 0; q < 4; ++q)
    o[q] = __builtin_bit_cast(unsigned short, (_Float16)shv[c4 + q][r]);
  *(uint2*)(WlinT + (size_t)(tj * 32 + r) * 256 + ti * 32 + c4) =
      make_uint2((unsigned)o[0] | ((unsigned)o[1] << 16),
                 (unsigned)o[2] | ((unsigned)o[3] << 16));
}

// ---------------------------------------------------------------------------
// f16 MFMA GEMM, 128x128 tile, 4 waves (2x2), 4x4 16x16x32 tiles/wave.
// SPLIT=1: hi/lo split, 3 MFMAs/product (pass1). SPLIT=0: plain f16 (pass0).
// MODE 0: A = gather([emb[jcol]|rel]); epi: leaky(+qt) -> Lr
// MODE 1: A = Lr;                      epi: +bc -> Rout f32
// MODE 2: A = gather([emb[icol]|rel]); epi: leaky(+qt), dot Rin,
//         16-lane reduce -> part[(nb*2+wn)][edge]   (deterministic)
// ---------------------------------------------------------------------------
template<int MODE, int SPLIT>
__global__ __launch_bounds__(256)
void gemm_kernel(const int* __restrict__ edges, int ebase,
                 const float* __restrict__ emb, const float* __restrict__ rel,
                 const unsigned* __restrict__ Apack,
                 const unsigned short* __restrict__ BtH,
                 const unsigned short* __restrict__ BtL,
                 const float* __restrict__ qt, const float* __restrict__ bcv,
                 unsigned* __restrict__ OutU,
                 const float* __restrict__ Rin,
                 float* __restrict__ part)
{
  __shared__ int sidx[128];
  __shared__ int sgrp[128];
  __shared__ unsigned bounce[64][132];

  const int tid  = threadIdx.x;
  const int lane = tid & 63;
  const int wid  = tid >> 6;
  const int wm = wid >> 1, wn = wid & 1;
  const int mb = blockIdx.x >> 2, nb = blockIdx.x & 3;
  const int rb = mb * 128;
  const int arow = lane & 15;
  const int kgrp = (lane >> 4) * 8;
  const int col0 = nb * 128 + wn * 64;
  const int row0 = wm * 64;

  if (MODE != 1) {
    if (tid < 128) {
      const int* er = edges + (size_t)(ebase + rb + tid) * 8;
      sidx[tid] = er[MODE == 0 ? 7 : 6];
      sgrp[tid] = er[0];
    }
    __syncthreads();
  }

  f32x4 acc[4][4];
#pragma unroll
  for (int a = 0; a < 4; ++a)
#pragma unroll
    for (int b = 0; b < 4; ++b) acc[a][b] = (f32x4)0.0f;

  for (int ks = 0; ks < 16; ++ks) {
    const int k0 = ks * 32 + kgrp;
    h8v ah[4], al[4], bh[4], bl[4];
#pragma unroll
    for (int nt = 0; nt < 4; ++nt) {
      const size_t boff = (size_t)(col0 + nt * 16 + arow) * 512 + k0;
      bh[nt] = *(const h8v*)(BtH + boff);
      if (SPLIT) bl[nt] = *(const h8v*)(BtL + boff);
    }
#pragma unroll
    for (int mt = 0; mt < 4; ++mt) {
      const int rl = row0 + mt * 16 + arow;
      h8v h, l;
      if (MODE == 1) {
        if (SPLIT) {
          const unsigned* ap = Apack + (size_t)(rb + rl) * 512 + k0;
          uint4 p0 = *(const uint4*)ap;
          uint4 p1 = *(const uint4*)(ap + 4);
          unsigned u[8] = {p0.x, p0.y, p0.z, p0.w, p1.x, p1.y, p1.z, p1.w};
          i4v hv, lv;
#pragma unroll
          for (int d = 0; d < 4; ++d) {
            hv[d] = (int)((u[2*d] >> 16) | (u[2*d+1] & 0xffff0000u));
            lv[d] = (int)((u[2*d] & 0xffffu) | (u[2*d+1] << 16));
          }
          h = __builtin_bit_cast(h8v, hv);
          l = __builtin_bit_cast(h8v, lv);
        } else {
          h = *(const h8v*)((const unsigned short*)Apack + (size_t)(rb + rl) * 512 + k0);
        }
      } else {
        const float* src = (k0 < 256)
            ? emb + (size_t)sidx[rl] * DDIM + k0
            : rel + (size_t)(ebase + rb + rl) * DDIM + (k0 - 256);
        float4 f0 = *(const float4*)src;
        float4 f1 = *(const float4*)(src + 4);
        float v[8] = {f0.x, f0.y, f0.z, f0.w, f1.x, f1.y, f1.z, f1.w};
#pragma unroll
        for (int d = 0; d < 8; ++d) {
          _Float16 hh = (_Float16)v[d];
          h[d] = hh;
          if (SPLIT) l[d] = (_Float16)(v[d] - (float)hh);
        }
      }
      ah[mt] = h;
      if (SPLIT) al[mt] = l;
    }
#pragma unroll
    for (int mt = 0; mt < 4; ++mt)
#pragma unroll
      for (int nt = 0; nt < 4; ++nt) {
        acc[mt][nt] = mfma16(ah[mt], bh[nt], acc[mt][nt]);
        if (SPLIT) {
          acc[mt][nt] = mfma16(ah[mt], bl[nt], acc[mt][nt]);
          acc[mt][nt] = mfma16(al[mt], bh[nt], acc[mt][nt]);
        }
      }
  }

  if (MODE == 2) {
#pragma unroll
    for (int mt = 0; mt < 4; ++mt) {
#pragma unroll
      for (int reg = 0; reg < 4; ++reg) {
        const int rl = row0 + mt * 16 + (lane >> 4) * 4 + reg;
        const int g = sgrp[rl];
        float s = 0.0f;
#pragma unroll
        for (int nt = 0; nt < 4; ++nt) {
          const int c = col0 + nt * 16 + arow;
          float v = lrelu(acc[mt][nt][reg] + qt[(size_t)g * NH + c]);
          s += v * Rin[(size_t)(rb + rl) * 512 + c];
        }
        s += __shfl_xor(s, 1); s += __shfl_xor(s, 2);
        s += __shfl_xor(s, 4); s += __shfl_xor(s, 8);
        if ((lane & 15) == 0)
          part[(size_t)(nb * 2 + wn) * ETOT + ebase + rb + rl] = s;
      }
    }
    return;
  }

  unsigned pk[4][4][4];
#pragma unroll
  for (int mt = 0; mt < 4; ++mt)
#pragma unroll
    for (int nt = 0; nt < 4; ++nt) {
      const int c = col0 + nt * 16 + arow;
#pragma unroll
      for (int reg = 0; reg < 4; ++reg) {
        const int rl = row0 + mt * 16 + (lane >> 4) * 4 + reg;
        float v = acc[mt][nt][reg];
        if (MODE == 0) {
          v = lrelu(v + qt[(size_t)sgrp[rl] * NH + c]);
          if (SPLIT) pk[mt][nt][reg] = packsplit(v);
          else pk[mt][nt][reg] =
              (unsigned)__builtin_bit_cast(unsigned short, (_Float16)v);
        } else {
          pk[mt][nt][reg] = __float_as_uint(v + bcv[c]);
        }
      }
    }
#pragma unroll
  for (int half = 0; half < 2; ++half) {
    __syncthreads();
    if (wm == half) {
#pragma unroll
      for (int mt = 0; mt < 4; ++mt)
#pragma unroll
        for (int nt = 0; nt < 4; ++nt) {
          const int cl = wn * 64 + nt * 16 + arow;
#pragma unroll
          for (int reg = 0; reg < 4; ++reg)
            bounce[mt * 16 + (lane >> 4) * 4 + reg][cl] = pk[mt][nt][reg];
        }
    }
    __syncthreads();
    if (MODE == 0 && SPLIT == 0) {
      const int r = tid >> 2, cb = (tid & 3) * 32;
      unsigned short* dst = (unsigned short*)OutU +
          (size_t)(rb + half * 64 + r) * 512 + nb * 128 + cb;
      unsigned pkk[16];
#pragma unroll
      for (int q = 0; q < 16; ++q) {
        unsigned a = bounce[r][cb + 2 * q], b = bounce[r][cb + 2 * q + 1];
        pkk[q] = (a & 0xffffu) | (b << 16);
      }
#pragma unroll
      for (int q = 0; q < 4; ++q)
        *(uint4*)(dst + q * 16) = *(uint4*)&pkk[q * 4];
    } else {
      const int r = tid >> 2, cb = (tid & 3) * 32;
      unsigned* dst = OutU + (size_t)(rb + half * 64 + r) * 512 + nb * 128 + cb;
      const unsigned* s0 = &bounce[r][cb];
#pragma unroll
      for (int q = 0; q < 8; ++q)
        *(uint4*)(dst + q * 4) = *(const uint4*)(s0 + q * 4);
    }
  }
}

// logits[e] = sum_p part[p][e] (fixed order), then segment-max via atomicMax
__global__ void reduce_max_kernel(const float* __restrict__ part,
                                  const int* __restrict__ edges,
                                  float* __restrict__ logits,
                                  unsigned* __restrict__ mkey, int E)
{
  int e = blockIdx.x * blockDim.x + threadIdx.x;
  if (e < E) {
    float s = 0.0f;
#pragma unroll
    for (int p = 0; p < 8; ++p) s += part[(size_t)p * ETOT + e];
    logits[e] = s;
    atomicMax(mkey + edges[(size_t)e * 8 + 6], fenc(s));
  }
}

__global__ void smax_exp_kernel(const int* __restrict__ edges, const float* __restrict__ logits,
                                const unsigned* __restrict__ mkey, float* __restrict__ ssum,
                                float* __restrict__ sm, int* __restrict__ cnt, int E)
{
  int e = blockIdx.x * blockDim.x + threadIdx.x;
  if (e < E) {
    int s = edges[(size_t)e * 8 + 6];
    float ev = expf(logits[e] - fdec(mkey[s]));
    sm[e] = ev;
    atomicAdd(ssum + s, ev);
    if (cnt) atomicAdd(cnt + edges[(size_t)e * 8 + 7], 1);
  }
}

__global__ void smax_norm_kernel(const int* __restrict__ edges, const float* __restrict__ ssum,
                                 float* __restrict__ sm, const float* __restrict__ nscore,
                                 float* __restrict__ ta, int E)
{
  int e = blockIdx.x * blockDim.x + threadIdx.x;
  if (e < E) {
    int s = edges[(size_t)e * 8 + 6];
    float v = sm[e] / ssum[s];
    sm[e] = v;
    if (ta) ta[e] = v * nscore[s];
  }
}

// ---------------------------------------------------------------------------
// per-group top-256 of 1024 (desc value, ties -> low idx), bitonic sort
// ---------------------------------------------------------------------------
__global__ __launch_bounds__(256)
void topk_kernel(const float* __restrict__ ta, const float* __restrict__ sm1,
                 const int* __restrict__ edges1,
                 float* __restrict__ out0, float* __restrict__ out2,
                 float* __restrict__ out3, float* __restrict__ smp,
                 int* __restrict__ prn_i, int* __restrict__ prn_j,
                 int* __restrict__ cnt1)
{
  __shared__ float v[EPG];
  __shared__ int   ix[EPG];
  const int g = blockIdx.x, tid = threadIdx.x;
  for (int t = tid; t < EPG; t += 256) { v[t] = ta[(size_t)g * EPG + t]; ix[t] = t; }
  __syncthreads();
  for (int k = 2; k <= EPG; k <<= 1) {
    for (int j = k >> 1; j > 0; j >>= 1) {
      for (int t = tid; t < EPG; t += 256) {
        int l = t ^ j;
        if (l > t) {
          float va = v[t], vb = v[l];
          int ia = ix[t], ib = ix[l];
          bool aFirst = (va > vb) || (va == vb && ia < ib);
          bool up = ((t & k) == 0);
          bool sw = up ? !aFirst : aFirst;
          if (sw) { v[t] = vb; ix[t] = ib; v[l] = va; ix[l] = ia; }
        }
      }
      __syncthreads();
    }
  }
  const int r = tid;
  const int oi = ix[r];
  const float val = v[r];
  const int orig = g * EPG + oi;
  out3[(size_t)g * KTOP + r] = (float)orig;
  const int* er = edges1 + (size_t)orig * 8;
#pragma unroll
  for (int c = 0; c < 8; ++c)
    out2[((size_t)(g * KTOP + r)) * 8 + c] = (float)er[c];
  const int ii = er[6], jj = er[7];
  const float smv = sm1[orig];
  smp[(size_t)g * KTOP + r] = smv;
  prn_i[(size_t)g * KTOP + r] = ii;
  prn_j[(size_t)g * KTOP + r] = jj;
  atomicAdd(out0 + jj, smv * val);
  atomicAdd(cnt1 + jj, 1);
}

// 4 edges per block; thread o = dim o
__global__ void scatter_kernel(const int* __restrict__ idx_i, int si,
                               const int* __restrict__ idx_j, int sj,
                               const float* __restrict__ w,
                               const float* __restrict__ semb,
                               float* __restrict__ agg)
{
  const int e0 = blockIdx.x * 4;
  const int o = threadIdx.x;
#pragma unroll
  for (int q = 0; q < 4; ++q) {
    const int e = e0 + q;
    const int i = idx_i[(size_t)e * si];
    const int j = idx_j[(size_t)e * sj];
    atomicAdd(agg + (size_t)j * DDIM + o, w[e] * semb[(size_t)i * DDIM + o]);
  }
}

__global__ void combine_kernel(const float* __restrict__ mememb, const int* __restrict__ cnt,
                               float* __restrict__ agg)
{
  size_t id = (size_t)blockIdx.x * 256 + threadIdx.x;
  if (cnt[id >> 8] == 0) agg[id] = mememb[id];
}

// ---------------------------------------------------------------------------
// final (MFMA f16): out[r] = leaky( (cnt0[r]>0 ? agg0[r] : emb1[r]) @ Wlin + blin )
// 512 threads = 8 waves (2 row x 4 col), block = 128 rows x 256 cols (ALL cols
// so the in-place out1 read/write has no cross-block race). K = 256.
// ---------------------------------------------------------------------------
__global__ __launch_bounds__(512)
void final_mfma_kernel(const float* __restrict__ emb1, const float* __restrict__ agg0,
                       const int* __restrict__ cnt0,
                       const unsigned short* __restrict__ WlinT,
                       const float* __restrict__ blin, float* __restrict__ out)
{
  __shared__ int scnt[128];
  const int tid  = threadIdx.x;
  const int lane = tid & 63;
  const int wid  = tid >> 6;
  const int wm = wid >> 2, wn = wid & 3;
  const int rb = blockIdx.x * 128;
  const int arow = lane & 15;
  const int kgrp = (lane >> 4) * 8;
  const int row0 = wm * 64;
  const int col0 = wn * 64;

  if (tid < 128) {
    int r = rb + tid;
    scnt[tid] = (r < NNODES) ? cnt0[(r < NNODES) ? r : 0] : 0;
  }
  __syncthreads();

  f32x4 acc[4][4];
#pragma unroll
  for (int a = 0; a < 4; ++a)
#pragma unroll
    for (int b = 0; b < 4; ++b) acc[a][b] = (f32x4)0.0f;

  for (int ks = 0; ks < 8; ++ks) {
    const int k0 = ks * 32 + kgrp;
    h8v ah[4], bh[4];
#pragma unroll
    for (int nt = 0; nt < 4; ++nt)
      bh[nt] = *(const h8v*)(WlinT + (size_t)(col0 + nt * 16 + arow) * 256 + k0);
#pragma unroll
    for (int mt = 0; mt < 4; ++mt) {
      const int rl = row0 + mt * 16 + arow;
      int r = rb + rl;
      int rc = (r < NNODES) ? r : (NNODES - 1);
      const float* base = (scnt[rl] > 0) ? agg0 : emb1;
      const float* src = base + (size_t)rc * DDIM + k0;
      float4 f0 = *(const float4*)src;
      float4 f1 = *(const float4*)(src + 4);
      float v[8] = {f0.x, f0.y, f0.z, f0.w, f1.x, f1.y, f1.z, f1.w};
      h8v h;
#pragma unroll
      for (int d = 0; d < 8; ++d) h[d] = (_Float16)v[d];
      ah[mt] = h;
    }
#pragma unroll
    for (int mt = 0; mt < 4; ++mt)
#pragma unroll
      for (int nt = 0; nt < 4; ++nt)
        acc[mt][nt] = mfma16(ah[mt], bh[nt], acc[mt][nt]);
  }

  float bl4[4];
#pragma unroll
  for (int nt = 0; nt < 4; ++nt) bl4[nt] = blin[col0 + nt * 16 + arow];

#pragma unroll
  for (int mt = 0; mt < 4; ++mt)
#pragma unroll
    for (int reg = 0; reg < 4; ++reg) {
      const int r = rb + row0 + mt * 16 + (lane >> 4) * 4 + reg;
      if (r < NNODES) {
#pragma unroll
        for (int nt = 0; nt < 4; ++nt) {
          const int c = col0 + nt * 16 + arow;
          out[(size_t)r * DDIM + c] = lrelu(acc[mt][nt][reg] + bl4[nt]);
        }
      }
    }
}

// ---------------------------------------------------------------------------
extern "C" void kernel_launch(void* const* d_in, const int* in_sizes, int n_in,
                              void* d_out, int out_size, void* d_ws, size_t ws_size,
                              hipStream_t stream)
{
  (void)in_sizes; (void)n_in; (void)out_size;

  const float* node_score = (const float*)d_in[1];
  const int*   edges0 = (const int*)d_in[2];
  const int*   edges1 = (const int*)d_in[3];
  const float* rel0   = (const float*)d_in[4];
  const float* rel1   = (const float*)d_in[5];
  const float* mememb = (const float*)d_in[6];
  const float* qse    = (const float*)d_in[7];
  const float* qre    = (const float*)d_in[8];
  const float* Wl     = (const float*)d_in[9];
  const float* bl     = (const float*)d_in[10];
  const float* Wr     = (const float*)d_in[11];
  const float* br     = (const float*)d_in[12];
  const float* Wc     = (const float*)d_in[13];
  const float* bc     = (const float*)d_in[14];
  const float* Wlin   = (const float*)d_in[15];
  const float* blin   = (const float*)d_in[16];

  float* out0 = (float*)d_out;
  float* out1 = out0 + NNODES;
  float* out2 = out1 + (size_t)NNODES * DDIM;
  float* out3 = out2 + (size_t)NGROUP * KTOP * 8;

  char* wptr = (char*)d_ws;
  auto alloc = [&](size_t bytes) -> char* {
    char* p = wptr;
    wptr += (bytes + 255) & ~(size_t)255;
    return p;
  };
  float*    qtl     = (float*)alloc((size_t)NGROUP * NH * 4);
  float*    qtr     = (float*)alloc((size_t)NGROUP * NH * 4);
  float*    logits1 = (float*)alloc((size_t)E1N * 4);
  float*    sm1     = (float*)alloc((size_t)E1N * 4);
  float*    ta      = (float*)alloc((size_t)E1N * 4);
  float*    logits0 = (float*)alloc((size_t)E0N * 4);
  float*    sm0     = (float*)alloc((size_t)E0N * 4);
  unsigned* mkey    = (unsigned*)alloc((size_t)NNODES * 4);
  float*    ssum    = (float*)alloc((size_t)NNODES * 4);
  int*      cnt1    = (int*)alloc((size_t)NNODES * 4);
  int*      cnt0    = (int*)alloc((size_t)NNODES * 4);
  float*    smp     = (float*)alloc((size_t)NGROUP * KTOP * 4);
  int*      prn_i   = (int*)alloc((size_t)NGROUP * KTOP * 4);
  int*      prn_j   = (int*)alloc((size_t)NGROUP * KTOP * 4);
  float*    part    = (float*)alloc((size_t)8 * ETOT * 4);        // 2 MB
  float*    agg1    = (float*)alloc((size_t)NNODES * DDIM * 4);   // emb1

  unsigned short* WltH = (unsigned short*)alloc((size_t)512 * 512 * 2);
  unsigned short* WltL = (unsigned short*)alloc((size_t)512 * 512 * 2);
  unsigned short* WrtH = (unsigned short*)alloc((size_t)512 * 512 * 2);
  unsigned short* WrtL = (unsigned short*)alloc((size_t)512 * 512 * 2);
  unsigned short* WctH = (unsigned short*)alloc((size_t)512 * 512 * 2);
  unsigned short* WctL = (unsigned short*)alloc((size_t)512 * 512 * 2);
  unsigned short* WlnT = (unsigned short*)alloc((size_t)256 * 256 * 2);

  // adaptive chunking of the GEMM pipeline to fit workspace (try 1 first!)
  size_t used = (size_t)(wptr - (char*)d_ws);
  int nchunks = 1;
  while (nchunks < 32 && used + 2 * ((size_t)(ETOT / nchunks) * 512 * 4 + 256) > ws_size)
    nchunks <<= 1;
  const int CE = ETOT / nchunks;
  unsigned* Lr   = (unsigned*)alloc((size_t)CE * 512 * 4);
  float*    Rout = (float*)alloc((size_t)CE * 512 * 4);

  // ---- pass 1 prep ----
  (void)hipMemsetAsync(agg1, 0, (size_t)NNODES * DDIM * 4, stream);
  (void)hipMemsetAsync(cnt1, 0, (size_t)NNODES * 4, stream);
  (void)hipMemsetAsync(mkey, 0, (size_t)NNODES * 4, stream);
  (void)hipMemsetAsync(ssum, 0, (size_t)NNODES * 4, stream);
  (void)hipMemsetAsync(out0, 0, (size_t)NNODES * 4, stream);

  qterm_kernel<<<NGROUP, 512, 0, stream>>>(qse, qre, Wl, bl, Wr, br, qtl, qtr);
  {
    dim3 g(256, 3);
    wprep_kernel<<<g, 256, 0, stream>>>(Wl, Wr, Wc, WltH, WltL, WrtH, WrtL, WctH, WctL);
  }
  wlinprep_kernel<<<64, 256, 0, stream>>>(Wlin, WlnT);

  // ---- pass 1: SPLIT=1 GEMM trio ----
  for (int ch = 0; ch < nchunks; ++ch) {
    const int eb = ch * CE;
    dim3 g((CE / 128) * 4);
    gemm_kernel<0,1><<<g, 256, 0, stream>>>(edges1, eb, mememb, rel1, nullptr,
                                            WrtH, WrtL, qtr, nullptr,
                                            Lr, nullptr, nullptr);
    gemm_kernel<1,1><<<g, 256, 0, stream>>>(edges1, eb, mememb, rel1, Lr,
                                            WctH, WctL, nullptr, bc,
                                            (unsigned*)Rout, nullptr, nullptr);
    gemm_kernel<2,1><<<g, 256, 0, stream>>>(edges1, eb, mememb, rel1, nullptr,
                                            WltH, WltL, qtl, nullptr,
                                            nullptr, Rout, part);
  }
  reduce_max_kernel<<<E1N / 256, 256, 0, stream>>>(part, edges1, logits1, mkey, E1N);
  smax_exp_kernel<<<E1N / 256, 256, 0, stream>>>(edges1, logits1, mkey, ssum, sm1,
                                                 nullptr, E1N);
  smax_norm_kernel<<<E1N / 256, 256, 0, stream>>>(edges1, ssum, sm1, node_score, ta, E1N);
  topk_kernel<<<NGROUP, 256, 0, stream>>>(ta, sm1, edges1, out0, out2, out3,
                                          smp, prn_i, prn_j, cnt1);
  scatter_kernel<<<NGROUP * KTOP / 4, 256, 0, stream>>>(prn_i, 1, prn_j, 1, smp,
                                                        mememb, agg1);
  combine_kernel<<<NNODES, 256, 0, stream>>>(mememb, cnt1, agg1);   // agg1 = emb1

  // ---- pass 0 prep ----
  (void)hipMemsetAsync(mkey, 0, (size_t)NNODES * 4, stream);
  (void)hipMemsetAsync(ssum, 0, (size_t)NNODES * 4, stream);
  (void)hipMemsetAsync(cnt0, 0, (size_t)NNODES * 4, stream);
  (void)hipMemsetAsync(out1, 0, (size_t)NNODES * DDIM * 4, stream);

  // ---- pass 0: SPLIT=0 GEMM trio ----
  for (int ch = 0; ch < nchunks; ++ch) {
    const int eb = ch * CE;
    dim3 g((CE / 128) * 4);
    gemm_kernel<0,0><<<g, 256, 0, stream>>>(edges0, eb, agg1, rel0, nullptr,
                                            WrtH, WrtL, qtr, nullptr,
                                            Lr, nullptr, nullptr);
    gemm_kernel<1,0><<<g, 256, 0, stream>>>(edges0, eb, agg1, rel0, Lr,
                                            WctH, WctL, nullptr, bc,
                                            (unsigned*)Rout, nullptr, nullptr);
    gemm_kernel<2,0><<<g, 256, 0, stream>>>(edges0, eb, agg1, rel0, nullptr,
                                            WltH, WltL, qtl, nullptr,
                                            nullptr, Rout, part);
  }
  reduce_max_kernel<<<E0N / 256, 256, 0, stream>>>(part, edges0, logits0, mkey, E0N);
  smax_exp_kernel<<<E0N / 256, 256, 0, stream>>>(edges0, logits0, mkey, ssum, sm0,
                                                 cnt0, E0N);
  smax_norm_kernel<<<E0N / 256, 256, 0, stream>>>(edges0, ssum, sm0, nullptr, nullptr, E0N);
  scatter_kernel<<<E0N / 4, 256, 0, stream>>>(edges0 + 6, 8, edges0 + 7, 8, sm0,
                                              agg1, out1);
  final_mfma_kernel<<<(NNODES + 127) / 128, 512, 0, stream>>>(agg1, out1, cnt0,
                                                              WlnT, blin, out1);
}

// Round 7
// 1766.367 us; speedup vs baseline: 1.8672x; 1.0115x over previous
//
#include <hip/hip_runtime.h>
#include <math.h>

// ---------------------------------------------------------------------------
// AttentionFlow v7.
//  = v6 + XCD-aware block swizzle in gemm_kernel (T1).
//  v6 counters: gemm dispatches FETCH 269 MB vs 128 MB unique A -> ~4x A
//  re-fetch because the 4 nb col-blocks of a row-tile land on 4 different
//  XCD-private L2s (consecutive blockIdx round-robin across 8 XCDs).
//  Swizzle maps all 4 nb blocks of one tile to the SAME XCD in adjacent
//  dispatch slots -> A fetched once into that L2, hit 3x.
// ---------------------------------------------------------------------------

#define NNODES 100000
#define DDIM   256
#define NH     512
#define NGROUP 64
#define EPG    1024
#define E1N    65536
#define E0N    65536
#define KTOP   256
#define ETOT   65536

typedef __attribute__((ext_vector_type(8))) _Float16 h8v;
typedef __attribute__((ext_vector_type(4))) float f32x4;
typedef __attribute__((ext_vector_type(4))) int i4v;

__device__ __forceinline__ float lrelu(float x) { return x > 0.0f ? x : 0.01f * x; }

__device__ __forceinline__ unsigned fenc(float f) {
  unsigned u = __float_as_uint(f);
  return (u & 0x80000000u) ? ~u : (u | 0x80000000u);
}
__device__ __forceinline__ float fdec(unsigned k) {
  unsigned u = (k & 0x80000000u) ? (k & 0x7FFFFFFFu) : ~k;
  return __uint_as_float(u);
}

__device__ __forceinline__ void splitf(float v, unsigned short& h, unsigned short& l) {
  _Float16 hh = (_Float16)v;
  _Float16 ll = (_Float16)(v - (float)hh);
  h = __builtin_bit_cast(unsigned short, hh);
  l = __builtin_bit_cast(unsigned short, ll);
}

__device__ __forceinline__ unsigned packsplit(float v) {
  unsigned short h, l;
  splitf(v, h, l);
  return ((unsigned)h << 16) | (unsigned)l;
}

__device__ __forceinline__ f32x4 mfma16(h8v a, h8v b, f32x4 c) {
  return __builtin_amdgcn_mfma_f32_16x16x32_f16(a, b, c, 0, 0, 0);
}

// ---------------------------------------------------------------------------
// qterm[g][o] = b[o] + qs[g] @ W[512:768] + qr[g] @ W[768:1024]
// ---------------------------------------------------------------------------
__global__ __launch_bounds__(512)
void qterm_kernel(const float* __restrict__ qse, const float* __restrict__ qre,
                  const float* __restrict__ Wl, const float* __restrict__ bl,
                  const float* __restrict__ Wr, const float* __restrict__ br,
                  float* __restrict__ qtl, float* __restrict__ qtr)
{
  const int g = blockIdx.x;
  const int o = threadIdx.x;
  __shared__ float sq[DDIM];
  __shared__ float sr[DDIM];
  if (o < DDIM) sq[o] = qse[(size_t)g * DDIM + o];
  else          sr[o - DDIM] = qre[(size_t)g * DDIM + (o - DDIM)];
  __syncthreads();
  float al = bl[o], ar = br[o];
  for (int k = 0; k < DDIM; ++k) {
    float a = sq[k], b = sr[k];
    al += a * Wl[(size_t)(512 + k) * NH + o] + b * Wl[(size_t)(768 + k) * NH + o];
    ar += a * Wr[(size_t)(512 + k) * NH + o] + b * Wr[(size_t)(768 + k) * NH + o];
  }
  qtl[(size_t)g * NH + o] = al;
  qtr[(size_t)g * NH + o] = ar;
}

// ---------------------------------------------------------------------------
// weight prep: Wt{H,L}[o][k] = splitf16(W[k][o]) for Wl[0:512], Wr[0:512], Wc
// ---------------------------------------------------------------------------
__global__ __launch_bounds__(256)
void wprep_kernel(const float* __restrict__ Wl, const float* __restrict__ Wr,
                  const float* __restrict__ Wc,
                  unsigned short* __restrict__ WltH, unsigned short* __restrict__ WltL,
                  unsigned short* __restrict__ WrtH, unsigned short* __restrict__ WrtL,
                  unsigned short* __restrict__ WctH, unsigned short* __restrict__ WctL)
{
  __shared__ float shv[32][33];
  const int mtx = blockIdx.y;
  const int ti = blockIdx.x >> 4;     // k tile
  const int tj = blockIdx.x & 15;     // o tile
  const float* W = mtx == 0 ? Wl : (mtx == 1 ? Wr : Wc);
  unsigned short* OH = mtx == 0 ? WltH : (mtx == 1 ? WrtH : WctH);
  unsigned short* OL = mtx == 0 ? WltL : (mtx == 1 ? WrtL : WctL);
  const int t = threadIdx.x;
  const int r = t >> 3, c4 = (t & 7) * 4;
  *(float4*)&shv[r][c4] = *(const float4*)(W + (size_t)(ti * 32 + r) * 512 + tj * 32 + c4);
  __syncthreads();
  unsigned short h[4], l[4];
#pragma unroll
  for (int q = 0; q < 4; ++q) splitf(shv[c4 + q][r], h[q], l[q]);
  const size_t off = (size_t)(tj * 32 + r) * 512 + ti * 32 + c4;
  *(uint2*)(OH + off) = make_uint2((unsigned)h[0] | ((unsigned)h[1] << 16),
                                   (unsigned)h[2] | ((unsigned)h[3] << 16));
  *(uint2*)(OL + off) = make_uint2((unsigned)l[0] | ((unsigned)l[1] << 16),
                                   (unsigned)l[2] | ((unsigned)l[3] << 16));
}

// WlinT[o][k] = f16(Wlin[k][o]), 256x256, hi only
__global__ __launch_bounds__(256)
void wlinprep_kernel(const float* __restrict__ Wlin, unsigned short* __restrict__ WlinT)
{
  __shared__ float shv[32][33];
  const int ti = blockIdx.x >> 3;    // k tile
  const int tj = blockIdx.x & 7;     // o tile
  const int t = threadIdx.x;
  const int r = t >> 3, c4 = (t & 7) * 4;
  *(float4*)&shv[r][c4] = *(const float4*)(Wlin + (size_t)(ti * 32 + r) * 256 + tj * 32 + c4);
  __syncthreads();
  unsigned short o[4];
#pragma unroll
  for (int q = 0; q < 4; ++q)
    o[q] = __builtin_bit_cast(unsigned short, (_Float16)shv[c4 + q][r]);
  *(uint2*)(WlinT + (size_t)(tj * 32 + r) * 256 + ti * 32 + c4) =
      make_uint2((unsigned)o[0] | ((unsigned)o[1] << 16),
                 (unsigned)o[2] | ((unsigned)o[3] << 16));
}

// ---------------------------------------------------------------------------
// f16 MFMA GEMM, 128x128 tile, 4 waves (2x2), 4x4 16x16x32 tiles/wave.
// SPLIT=1: hi/lo split, 3 MFMAs/product (pass1). SPLIT=0: plain f16 (pass0).
// MODE 0: A = gather([emb[jcol]|rel]); epi: leaky(+qt) -> Lr
// MODE 1: A = Lr;                      epi: +bc -> Rout f32
// MODE 2: A = gather([emb[icol]|rel]); epi: leaky(+qt), dot Rin,
//         16-lane reduce -> part[(nb*2+wn)][edge]   (deterministic)
// XCD swizzle: all 4 nb col-blocks of one row-tile -> same XCD, adjacent slots.
// ---------------------------------------------------------------------------
template<int MODE, int SPLIT>
__global__ __launch_bounds__(256)
void gemm_kernel(const int* __restrict__ edges, int ebase,
                 const float* __restrict__ emb, const float* __restrict__ rel,
                 const unsigned* __restrict__ Apack,
                 const unsigned short* __restrict__ BtH,
                 const unsigned short* __restrict__ BtL,
                 const float* __restrict__ qt, const float* __restrict__ bcv,
                 unsigned* __restrict__ OutU,
                 const float* __restrict__ Rin,
                 float* __restrict__ part)
{
  __shared__ int sidx[128];
  __shared__ int sgrp[128];
  __shared__ unsigned bounce[64][132];

  const int tid  = threadIdx.x;
  const int lane = tid & 63;
  const int wid  = tid >> 6;
  const int wm = wid >> 1, wn = wid & 1;
  // ---- XCD-aware decode (T1): hw dispatch round-robins blockIdx across the
  // 8 XCD-private L2s; put the 4 nb-blocks of one tile on ONE XCD. ----
  const int T   = gridDim.x >> 2;          // row tiles (power of 2, >= 16)
  const int xcd = blockIdx.x & 7;
  const int slt = blockIdx.x >> 3;
  const int mb  = xcd * (T >> 3) + (slt >> 2);
  const int nb  = slt & 3;
  const int rb = mb * 128;
  const int arow = lane & 15;
  const int kgrp = (lane >> 4) * 8;
  const int col0 = nb * 128 + wn * 64;
  const int row0 = wm * 64;

  if (MODE != 1) {
    if (tid < 128) {
      const int* er = edges + (size_t)(ebase + rb + tid) * 8;
      sidx[tid] = er[MODE == 0 ? 7 : 6];
      sgrp[tid] = er[0];
    }
    __syncthreads();
  }

  f32x4 acc[4][4];
#pragma unroll
  for (int a = 0; a < 4; ++a)
#pragma unroll
    for (int b = 0; b < 4; ++b) acc[a][b] = (f32x4)0.0f;

  for (int ks = 0; ks < 16; ++ks) {
    const int k0 = ks * 32 + kgrp;
    h8v ah[4], al[4], bh[4], bl[4];
#pragma unroll
    for (int nt = 0; nt < 4; ++nt) {
      const size_t boff = (size_t)(col0 + nt * 16 + arow) * 512 + k0;
      bh[nt] = *(const h8v*)(BtH + boff);
      if (SPLIT) bl[nt] = *(const h8v*)(BtL + boff);
    }
#pragma unroll
    for (int mt = 0; mt < 4; ++mt) {
      const int rl = row0 + mt * 16 + arow;
      h8v h, l;
      if (MODE == 1) {
        if (SPLIT) {
          const unsigned* ap = Apack + (size_t)(rb + rl) * 512 + k0;
          uint4 p0 = *(const uint4*)ap;
          uint4 p1 = *(const uint4*)(ap + 4);
          unsigned u[8] = {p0.x, p0.y, p0.z, p0.w, p1.x, p1.y, p1.z, p1.w};
          i4v hv, lv;
#pragma unroll
          for (int d = 0; d < 4; ++d) {
            hv[d] = (int)((u[2*d] >> 16) | (u[2*d+1] & 0xffff0000u));
            lv[d] = (int)((u[2*d] & 0xffffu) | (u[2*d+1] << 16));
          }
          h = __builtin_bit_cast(h8v, hv);
          l = __builtin_bit_cast(h8v, lv);
        } else {
          h = *(const h8v*)((const unsigned short*)Apack + (size_t)(rb + rl) * 512 + k0);
        }
      } else {
        const float* src = (k0 < 256)
            ? emb + (size_t)sidx[rl] * DDIM + k0
            : rel + (size_t)(ebase + rb + rl) * DDIM + (k0 - 256);
        float4 f0 = *(const float4*)src;
        float4 f1 = *(const float4*)(src + 4);
        float v[8] = {f0.x, f0.y, f0.z, f0.w, f1.x, f1.y, f1.z, f1.w};
#pragma unroll
        for (int d = 0; d < 8; ++d) {
          _Float16 hh = (_Float16)v[d];
          h[d] = hh;
          if (SPLIT) l[d] = (_Float16)(v[d] - (float)hh);
        }
      }
      ah[mt] = h;
      if (SPLIT) al[mt] = l;
    }
#pragma unroll
    for (int mt = 0; mt < 4; ++mt)
#pragma unroll
      for (int nt = 0; nt < 4; ++nt) {
        acc[mt][nt] = mfma16(ah[mt], bh[nt], acc[mt][nt]);
        if (SPLIT) {
          acc[mt][nt] = mfma16(ah[mt], bl[nt], acc[mt][nt]);
          acc[mt][nt] = mfma16(al[mt], bh[nt], acc[mt][nt]);
        }
      }
  }

  if (MODE == 2) {
#pragma unroll
    for (int mt = 0; mt < 4; ++mt) {
#pragma unroll
      for (int reg = 0; reg < 4; ++reg) {
        const int rl = row0 + mt * 16 + (lane >> 4) * 4 + reg;
        const int g = sgrp[rl];
        float s = 0.0f;
#pragma unroll
        for (int nt = 0; nt < 4; ++nt) {
          const int c = col0 + nt * 16 + arow;
          float v = lrelu(acc[mt][nt][reg] + qt[(size_t)g * NH + c]);
          s += v * Rin[(size_t)(rb + rl) * 512 + c];
        }
        s += __shfl_xor(s, 1); s += __shfl_xor(s, 2);
        s += __shfl_xor(s, 4); s += __shfl_xor(s, 8);
        if ((lane & 15) == 0)
          part[(size_t)(nb * 2 + wn) * ETOT + ebase + rb + rl] = s;
      }
    }
    return;
  }

  unsigned pk[4][4][4];
#pragma unroll
  for (int mt = 0; mt < 4; ++mt)
#pragma unroll
    for (int nt = 0; nt < 4; ++nt) {
      const int c = col0 + nt * 16 + arow;
#pragma unroll
      for (int reg = 0; reg < 4; ++reg) {
        const int rl = row0 + mt * 16 + (lane >> 4) * 4 + reg;
        float v = acc[mt][nt][reg];
        if (MODE == 0) {
          v = lrelu(v + qt[(size_t)sgrp[rl] * NH + c]);
          if (SPLIT) pk[mt][nt][reg] = packsplit(v);
          else pk[mt][nt][reg] =
              (unsigned)__builtin_bit_cast(unsigned short, (_Float16)v);
        } else {
          pk[mt][nt][reg] = __float_as_uint(v + bcv[c]);
        }
      }
    }
#pragma unroll
  for (int half = 0; half < 2; ++half) {
    __syncthreads();
    if (wm == half) {
#pragma unroll
      for (int mt = 0; mt < 4; ++mt)
#pragma unroll
        for (int nt = 0; nt < 4; ++nt) {
          const int cl = wn * 64 + nt * 16 + arow;
#pragma unroll
          for (int reg = 0; reg < 4; ++reg)
            bounce[mt * 16 + (lane >> 4) * 4 + reg][cl] = pk[mt][nt][reg];
        }
    }
    __syncthreads();
    if (MODE == 0 && SPLIT == 0) {
      const int r = tid >> 2, cb = (tid & 3) * 32;
      unsigned short* dst = (unsigned short*)OutU +
          (size_t)(rb + half * 64 + r) * 512 + nb * 128 + cb;
      unsigned pkk[16];
#pragma unroll
      for (int q = 0; q < 16; ++q) {
        unsigned a = bounce[r][cb + 2 * q], b = bounce[r][cb + 2 * q + 1];
        pkk[q] = (a & 0xffffu) | (b << 16);
      }
#pragma unroll
      for (int q = 0; q < 4; ++q)
        *(uint4*)(dst + q * 16) = *(uint4*)&pkk[q * 4];
    } else {
      const int r = tid >> 2, cb = (tid & 3) * 32;
      unsigned* dst = OutU + (size_t)(rb + half * 64 + r) * 512 + nb * 128 + cb;
      const unsigned* s0 = &bounce[r][cb];
#pragma unroll
      for (int q = 0; q < 8; ++q)
        *(uint4*)(dst + q * 4) = *(const uint4*)(s0 + q * 4);
    }
  }
}

// logits[e] = sum_p part[p][e] (fixed order), then segment-max via atomicMax
__global__ void reduce_max_kernel(const float* __restrict__ part,
                                  const int* __restrict__ edges,
                                  float* __restrict__ logits,
                                  unsigned* __restrict__ mkey, int E)
{
  int e = blockIdx.x * blockDim.x + threadIdx.x;
  if (e < E) {
    float s = 0.0f;
#pragma unroll
    for (int p = 0; p < 8; ++p) s += part[(size_t)p * ETOT + e];
    logits[e] = s;
    atomicMax(mkey + edges[(size_t)e * 8 + 6], fenc(s));
  }
}

__global__ void smax_exp_kernel(const int* __restrict__ edges, const float* __restrict__ logits,
                                const unsigned* __restrict__ mkey, float* __restrict__ ssum,
                                float* __restrict__ sm, int* __restrict__ cnt, int E)
{
  int e = blockIdx.x * blockDim.x + threadIdx.x;
  if (e < E) {
    int s = edges[(size_t)e * 8 + 6];
    float ev = expf(logits[e] - fdec(mkey[s]));
    sm[e] = ev;
    atomicAdd(ssum + s, ev);
    if (cnt) atomicAdd(cnt + edges[(size_t)e * 8 + 7], 1);
  }
}

__global__ void smax_norm_kernel(const int* __restrict__ edges, const float* __restrict__ ssum,
                                 float* __restrict__ sm, const float* __restrict__ nscore,
                                 float* __restrict__ ta, int E)
{
  int e = blockIdx.x * blockDim.x + threadIdx.x;
  if (e < E) {
    int s = edges[(size_t)e * 8 + 6];
    float v = sm[e] / ssum[s];
    sm[e] = v;
    if (ta) ta[e] = v * nscore[s];
  }
}

// ---------------------------------------------------------------------------
// per-group top-256 of 1024 (desc value, ties -> low idx), bitonic sort
// ---------------------------------------------------------------------------
__global__ __launch_bounds__(256)
void topk_kernel(const float* __restrict__ ta, const float* __restrict__ sm1,
                 const int* __restrict__ edges1,
                 float* __restrict__ out0, float* __restrict__ out2,
                 float* __restrict__ out3, float* __restrict__ smp,
                 int* __restrict__ prn_i, int* __restrict__ prn_j,
                 int* __restrict__ cnt1)
{
  __shared__ float v[EPG];
  __shared__ int   ix[EPG];
  const int g = blockIdx.x, tid = threadIdx.x;
  for (int t = tid; t < EPG; t += 256) { v[t] = ta[(size_t)g * EPG + t]; ix[t] = t; }
  __syncthreads();
  for (int k = 2; k <= EPG; k <<= 1) {
    for (int j = k >> 1; j > 0; j >>= 1) {
      for (int t = tid; t < EPG; t += 256) {
        int l = t ^ j;
        if (l > t) {
          float va = v[t], vb = v[l];
          int ia = ix[t], ib = ix[l];
          bool aFirst = (va > vb) || (va == vb && ia < ib);
          bool up = ((t & k) == 0);
          bool sw = up ? !aFirst : aFirst;
          if (sw) { v[t] = vb; ix[t] = ib; v[l] = va; ix[l] = ia; }
        }
      }
      __syncthreads();
    }
  }
  const int r = tid;
  const int oi = ix[r];
  const float val = v[r];
  const int orig = g * EPG + oi;
  out3[(size_t)g * KTOP + r] = (float)orig;
  const int* er = edges1 + (size_t)orig * 8;
#pragma unroll
  for (int c = 0; c < 8; ++c)
    out2[((size_t)(g * KTOP + r)) * 8 + c] = (float)er[c];
  const int ii = er[6], jj = er[7];
  const float smv = sm1[orig];
  smp[(size_t)g * KTOP + r] = smv;
  prn_i[(size_t)g * KTOP + r] = ii;
  prn_j[(size_t)g * KTOP + r] = jj;
  atomicAdd(out0 + jj, smv * val);
  atomicAdd(cnt1 + jj, 1);
}

// 4 edges per block; thread o = dim o
__global__ void scatter_kernel(const int* __restrict__ idx_i, int si,
                               const int* __restrict__ idx_j, int sj,
                               const float* __restrict__ w,
                               const float* __restrict__ semb,
                               float* __restrict__ agg)
{
  const int e0 = blockIdx.x * 4;
  const int o = threadIdx.x;
#pragma unroll
  for (int q = 0; q < 4; ++q) {
    const int e = e0 + q;
    const int i = idx_i[(size_t)e * si];
    const int j = idx_j[(size_t)e * sj];
    atomicAdd(agg + (size_t)j * DDIM + o, w[e] * semb[(size_t)i * DDIM + o]);
  }
}

__global__ void combine_kernel(const float* __restrict__ mememb, const int* __restrict__ cnt,
                               float* __restrict__ agg)
{
  size_t id = (size_t)blockIdx.x * 256 + threadIdx.x;
  if (cnt[id >> 8] == 0) agg[id] = mememb[id];
}

// ---------------------------------------------------------------------------
// final (MFMA f16): out[r] = leaky( (cnt0[r]>0 ? agg0[r] : emb1[r]) @ Wlin + blin )
// 512 threads = 8 waves (2 row x 4 col), block = 128 rows x 256 cols (ALL cols
// so the in-place out1 read/write has no cross-block race). K = 256.
// ---------------------------------------------------------------------------
__global__ __launch_bounds__(512)
void final_mfma_kernel(const float* __restrict__ emb1, const float* __restrict__ agg0,
                       const int* __restrict__ cnt0,
                       const unsigned short* __restrict__ WlinT,
                       const float* __restrict__ blin, float* __restrict__ out)
{
  __shared__ int scnt[128];
  const int tid  = threadIdx.x;
  const int lane = tid & 63;
  const int wid  = tid >> 6;
  const int wm = wid >> 2, wn = wid & 3;
  const int rb = blockIdx.x * 128;
  const int arow = lane & 15;
  const int kgrp = (lane >> 4) * 8;
  const int row0 = wm * 64;
  const int col0 = wn * 64;

  if (tid < 128) {
    int r = rb + tid;
    scnt[tid] = (r < NNODES) ? cnt0[(r < NNODES) ? r : 0] : 0;
  }
  __syncthreads();

  f32x4 acc[4][4];
#pragma unroll
  for (int a = 0; a < 4; ++a)
#pragma unroll
    for (int b = 0; b < 4; ++b) acc[a][b] = (f32x4)0.0f;

  for (int ks = 0; ks < 8; ++ks) {
    const int k0 = ks * 32 + kgrp;
    h8v ah[4], bh[4];
#pragma unroll
    for (int nt = 0; nt < 4; ++nt)
      bh[nt] = *(const h8v*)(WlinT + (size_t)(col0 + nt * 16 + arow) * 256 + k0);
#pragma unroll
    for (int mt = 0; mt < 4; ++mt) {
      const int rl = row0 + mt * 16 + arow;
      int r = rb + rl;
      int rc = (r < NNODES) ? r : (NNODES - 1);
      const float* base = (scnt[rl] > 0) ? agg0 : emb1;
      const float* src = base + (size_t)rc * DDIM + k0;
      float4 f0 = *(const float4*)src;
      float4 f1 = *(const float4*)(src + 4);
      float v[8] = {f0.x, f0.y, f0.z, f0.w, f1.x, f1.y, f1.z, f1.w};
      h8v h;
#pragma unroll
      for (int d = 0; d < 8; ++d) h[d] = (_Float16)v[d];
      ah[mt] = h;
    }
#pragma unroll
    for (int mt = 0; mt < 4; ++mt)
#pragma unroll
      for (int nt = 0; nt < 4; ++nt)
        acc[mt][nt] = mfma16(ah[mt], bh[nt], acc[mt][nt]);
  }

  float bl4[4];
#pragma unroll
  for (int nt = 0; nt < 4; ++nt) bl4[nt] = blin[col0 + nt * 16 + arow];

#pragma unroll
  for (int mt = 0; mt < 4; ++mt)
#pragma unroll
    for (int reg = 0; reg < 4; ++reg) {
      const int r = rb + row0 + mt * 16 + (lane >> 4) * 4 + reg;
      if (r < NNODES) {
#pragma unroll
        for (int nt = 0; nt < 4; ++nt) {
          const int c = col0 + nt * 16 + arow;
          out[(size_t)r * DDIM + c] = lrelu(acc[mt][nt][reg] + bl4[nt]);
        }
      }
    }
}

// ---------------------------------------------------------------------------
extern "C" void kernel_launch(void* const* d_in, const int* in_sizes, int n_in,
                              void* d_out, int out_size, void* d_ws, size_t ws_size,
                              hipStream_t stream)
{
  (void)in_sizes; (void)n_in; (void)out_size;

  const float* node_score = (const float*)d_in[1];
  const int*   edges0 = (const int*)d_in[2];
  const int*   edges1 = (const int*)d_in[3];
  const float* rel0   = (const float*)d_in[4];
  const float* rel1   = (const float*)d_in[5];
  const float* mememb = (const float*)d_in[6];
  const float* qse    = (const float*)d_in[7];
  const float* qre    = (const float*)d_in[8];
  const float* Wl     = (const float*)d_in[9];
  const float* bl     = (const float*)d_in[10];
  const float* Wr     = (const float*)d_in[11];
  const float* br     = (const float*)d_in[12];
  const float* Wc     = (const float*)d_in[13];
  const float* bc     = (const float*)d_in[14];
  const float* Wlin   = (const float*)d_in[15];
  const float* blin   = (const float*)d_in[16];

  float* out0 = (float*)d_out;
  float* out1 = out0 + NNODES;
  float* out2 = out1 + (size_t)NNODES * DDIM;
  float* out3 = out2 + (size_t)NGROUP * KTOP * 8;

  char* wptr = (char*)d_ws;
  auto alloc = [&](size_t bytes) -> char* {
    char* p = wptr;
    wptr += (bytes + 255) & ~(size_t)255;
    return p;
  };
  float*    qtl     = (float*)alloc((size_t)NGROUP * NH * 4);
  float*    qtr     = (float*)alloc((size_t)NGROUP * NH * 4);
  float*    logits1 = (float*)alloc((size_t)E1N * 4);
  float*    sm1     = (float*)alloc((size_t)E1N * 4);
  float*    ta      = (float*)alloc((size_t)E1N * 4);
  float*    logits0 = (float*)alloc((size_t)E0N * 4);
  float*    sm0     = (float*)alloc((size_t)E0N * 4);
  unsigned* mkey    = (unsigned*)alloc((size_t)NNODES * 4);
  float*    ssum    = (float*)alloc((size_t)NNODES * 4);
  int*      cnt1    = (int*)alloc((size_t)NNODES * 4);
  int*      cnt0    = (int*)alloc((size_t)NNODES * 4);
  float*    smp     = (float*)alloc((size_t)NGROUP * KTOP * 4);
  int*      prn_i   = (int*)alloc((size_t)NGROUP * KTOP * 4);
  int*      prn_j   = (int*)alloc((size_t)NGROUP * KTOP * 4);
  float*    part    = (float*)alloc((size_t)8 * ETOT * 4);        // 2 MB
  float*    agg1    = (float*)alloc((size_t)NNODES * DDIM * 4);   // emb1

  unsigned short* WltH = (unsigned short*)alloc((size_t)512 * 512 * 2);
  unsigned short* WltL = (unsigned short*)alloc((size_t)512 * 512 * 2);
  unsigned short* WrtH = (unsigned short*)alloc((size_t)512 * 512 * 2);
  unsigned short* WrtL = (unsigned short*)alloc((size_t)512 * 512 * 2);
  unsigned short* WctH = (unsigned short*)alloc((size_t)512 * 512 * 2);
  unsigned short* WctL = (unsigned short*)alloc((size_t)512 * 512 * 2);
  unsigned short* WlnT = (unsigned short*)alloc((size_t)256 * 256 * 2);

  // adaptive chunking of the GEMM pipeline to fit workspace (try 1 first)
  size_t used = (size_t)(wptr - (char*)d_ws);
  int nchunks = 1;
  while (nchunks < 32 && used + 2 * ((size_t)(ETOT / nchunks) * 512 * 4 + 256) > ws_size)
    nchunks <<= 1;
  const int CE = ETOT / nchunks;
  unsigned* Lr   = (unsigned*)alloc((size_t)CE * 512 * 4);
  float*    Rout = (float*)alloc((size_t)CE * 512 * 4);

  // ---- pass 1 prep ----
  (void)hipMemsetAsync(agg1, 0, (size_t)NNODES * DDIM * 4, stream);
  (void)hipMemsetAsync(cnt1, 0, (size_t)NNODES * 4, stream);
  (void)hipMemsetAsync(mkey, 0, (size_t)NNODES * 4, stream);
  (void)hipMemsetAsync(ssum, 0, (size_t)NNODES * 4, stream);
  (void)hipMemsetAsync(out0, 0, (size_t)NNODES * 4, stream);

  qterm_kernel<<<NGROUP, 512, 0, stream>>>(qse, qre, Wl, bl, Wr, br, qtl, qtr);
  {
    dim3 g(256, 3);
    wprep_kernel<<<g, 256, 0, stream>>>(Wl, Wr, Wc, WltH, WltL, WrtH, WrtL, WctH, WctL);
  }
  wlinprep_kernel<<<64, 256, 0, stream>>>(Wlin, WlnT);

  // ---- pass 1: SPLIT=1 GEMM trio ----
  for (int ch = 0; ch < nchunks; ++ch) {
    const int eb = ch * CE;
    dim3 g((CE / 128) * 4);
    gemm_kernel<0,1><<<g, 256, 0, stream>>>(edges1, eb, mememb, rel1, nullptr,
                                            WrtH, WrtL, qtr, nullptr,
                                            Lr, nullptr, nullptr);
    gemm_kernel<1,1><<<g, 256, 0, stream>>>(edges1, eb, mememb, rel1, Lr,
                                            WctH, WctL, nullptr, bc,
                                            (unsigned*)Rout, nullptr, nullptr);
    gemm_kernel<2,1><<<g, 256, 0, stream>>>(edges1, eb, mememb, rel1, nullptr,
                                            WltH, WltL, qtl, nullptr,
                                            nullptr, Rout, part);
  }
  reduce_max_kernel<<<E1N / 256, 256, 0, stream>>>(part, edges1, logits1, mkey, E1N);
  smax_exp_kernel<<<E1N / 256, 256, 0, stream>>>(edges1, logits1, mkey, ssum, sm1,
                                                 nullptr, E1N);
  smax_norm_kernel<<<E1N / 256, 256, 0, stream>>>(edges1, ssum, sm1, node_score, ta, E1N);
  topk_kernel<<<NGROUP, 256, 0, stream>>>(ta, sm1, edges1, out0, out2, out3,
                                          smp, prn_i, prn_j, cnt1);
  scatter_kernel<<<NGROUP * KTOP / 4, 256, 0, stream>>>(prn_i, 1, prn_j, 1, smp,
                                                        mememb, agg1);
  combine_kernel<<<NNODES, 256, 0, stream>>>(mememb, cnt1, agg1);   // agg1 = emb1

  // ---- pass 0 prep ----
  (void)hipMemsetAsync(mkey, 0, (size_t)NNODES * 4, stream);
  (void)hipMemsetAsync(ssum, 0, (size_t)NNODES * 4, stream);
  (void)hipMemsetAsync(cnt0, 0, (size_t)NNODES * 4, stream);
  (void)hipMemsetAsync(out1, 0, (size_t)NNODES * DDIM * 4, stream);

  // ---- pass 0: SPLIT=0 GEMM trio ----
  for (int ch = 0; ch < nchunks; ++ch) {
    const int eb = ch * CE;
    dim3 g((CE / 128) * 4);
    gemm_kernel<0,0><<<g, 256, 0, stream>>>(edges0, eb, agg1, rel0, nullptr,
                                            WrtH, WrtL, qtr, nullptr,
                                            Lr, nullptr, nullptr);
    gemm_kernel<1,0><<<g, 256, 0, stream>>>(edges0, eb, agg1, rel0, Lr,
                                            WctH, WctL, nullptr, bc,
                                            (unsigned*)Rout, nullptr, nullptr);
    gemm_kernel<2,0><<<g, 256, 0, stream>>>(edges0, eb, agg1, rel0, nullptr,
                                            WltH, WltL, qtl, nullptr,
                                            nullptr, Rout, part);
  }
  reduce_max_kernel<<<E0N / 256, 256, 0, stream>>>(part, edges0, logits0, mkey, E0N);
  smax_exp_kernel<<<E0N / 256, 256, 0, stream>>>(edges0, logits0, mkey, ssum, sm0,
                                                 cnt0, E0N);
  smax_norm_kernel<<<E0N / 256, 256, 0, stream>>>(edges0, ssum, sm0, nullptr, nullptr, E0N);
  scatter_kernel<<<E0N / 4, 256, 0, stream>>>(edges0 + 6, 8, edges0 + 7, 8, sm0,
                                              agg1, out1);
  final_mfma_kernel<<<(NNODES + 127) / 128, 512, 0, stream>>>(agg1, out1, cnt0,
                                                              WlnT, blin, out1);
}